// Round 2
// baseline (47322.656 us; speedup 1.0000x reference)
//
#include <hip/hip_runtime.h>
#include <stdint.h>

typedef _Float16 f16;
typedef _Float16 f16x8 __attribute__((ext_vector_type(8)));
typedef float f32x4 __attribute__((ext_vector_type(4)));

#define MFMA16(a, b, c) __builtin_amdgcn_mfma_f32_16x16x32_f16((a), (b), (c), 0, 0, 0)

// Sizes: B=64, S=512, I=512, H=1024, 4H=4096, O=64

// ---------------- prep kernels ----------------

// x (B,S,I) f32 -> x16 (S,B,I) f16
__global__ void k_conv_x(const float* __restrict__ x, f16* __restrict__ x16) {
  int s = blockIdx.x >> 6, b = blockIdx.x & 63;
  const float4* src = (const float4*)(x + ((size_t)b * 512 + s) * 512);
  f16* dst = x16 + (size_t)blockIdx.x * 512;
  int tid = threadIdx.x;
  float4 v = src[tid];
  union { f16 h[4]; uint64_t u; } tmp;
  tmp.h[0] = (f16)v.x; tmp.h[1] = (f16)v.y; tmp.h[2] = (f16)v.z; tmp.h[3] = (f16)v.w;
  *(uint64_t*)(dst + tid * 4) = tmp.u;
}

// Weight reorder + f32->f16. Dest row d: jb=d>>5, r=d&31, q=r>>3, jl=r&7,
// source gate row g = q*1024 + jb*8 + jl. Row = [Wih(g,:) | Whh(g,:)].
__global__ void k_conv_w(const float* __restrict__ Wih, const float* __restrict__ Whh,
                         const float* __restrict__ bih, const float* __restrict__ bhh,
                         f16* __restrict__ Wr, float* __restrict__ br, int KI) {
  int d = blockIdx.x;
  int jb = d >> 5, r = d & 31, q = r >> 3, jl = r & 7;
  int g = q * 1024 + jb * 8 + jl;
  int Ktot = KI + 1024;
  const float* src0 = Wih + (size_t)g * KI;
  const float* src1 = Whh + (size_t)g * 1024;
  f16* dst = Wr + (size_t)d * Ktot;
  for (int k = threadIdx.x; k < Ktot; k += blockDim.x) {
    float v = (k < KI) ? src0[k] : src1[k - KI];
    dst[k] = (f16)v;
  }
  if (threadIdx.x == 0) br[d] = bih[g] + bhh[g];
}

__global__ void k_conv_wfc(const float* __restrict__ Wfc, f16* __restrict__ Wfc16) {
  int i = blockIdx.x * 256 + threadIdx.x;
  Wfc16[i] = (f16)Wfc[i];
}

// ---------------- persistent pipelined LSTM ----------------
// 256 blocks x 512 threads, cooperative (all co-resident, 1 block/CU).
// Blocks 0..127: layer0 slab jb. Blocks 128..255: layer1 slab jb.
// Weights live in VGPRs for the whole kernel. Per-step sync via global
// semaphores: sem0[t] = #L0 blocks done writing h0_t, sem1[t] likewise.
// L0@t waits sem0[t-1]==128, sem1[t-2]==128 (WAR on h0 double buffer).
// L1@t waits sem0[t]==128, sem1[t-1]==128.
__global__ __launch_bounds__(512, 2)
void k_persist(const f16* __restrict__ x16,
               const f16* __restrict__ W0r, const float* __restrict__ b0r,
               const f16* __restrict__ W1r, const float* __restrict__ b1r,
               f16* __restrict__ h0b0, f16* __restrict__ h0b1,
               f16* __restrict__ h1b0, f16* __restrict__ h1b1,
               f16* __restrict__ h1all, int* sem0, int* sem1) {
  const int layer = blockIdx.x >> 7;
  const int jb = blockIdx.x & 127;
  __shared__ float cred[8][64][33];

  const int tid = threadIdx.x;
  const int w = tid >> 6, lane = tid & 63;
  const int l15 = lane & 15, ksub = (lane >> 4) << 3;
  const int m = tid >> 3, jl = tid & 7, jg = jb * 8 + jl;

  const float* bias = (layer ? b1r : b0r) + jb * 32;
  const float bI = bias[jl], bF = bias[8 + jl], bG = bias[16 + jl], bO = bias[24 + jl];
  float creg = 0.f;

  if (layer == 0) {
    const f16* Bs = W0r + (size_t)jb * 32 * 1536;
    const int kbeg = w * 192;
    f16x8 wreg[6][2];
#pragma unroll
    for (int kk = 0; kk < 6; ++kk)
#pragma unroll
      for (int cf = 0; cf < 2; ++cf)
        wreg[kk][cf] = *(const f16x8*)(Bs + (size_t)(cf * 16 + l15) * 1536 + (kbeg + kk * 32 + ksub));

    for (int t = 0; t < 512; ++t) {
      if (tid == 0) {
        if (t >= 1)
          while (__hip_atomic_load(&sem0[t - 1], __ATOMIC_RELAXED, __HIP_MEMORY_SCOPE_AGENT) < 128)
            __builtin_amdgcn_s_sleep(1);
        if (t >= 2)
          while (__hip_atomic_load(&sem1[t - 2], __ATOMIC_RELAXED, __HIP_MEMORY_SCOPE_AGENT) < 128)
            __builtin_amdgcn_s_sleep(1);
      }
      __syncthreads();
      __threadfence();  // acquire: see producers' h stores

      const f16* A0 = x16 + (size_t)t * 32768;
      const f16* A1 = (t & 1) ? h0b0 : h0b1;   // h0_{t-1}
      f16* hout = (t & 1) ? h0b1 : h0b0;       // h0_t

      f32x4 acc[4][2];
#pragma unroll
      for (int i = 0; i < 4; ++i) {
        acc[i][0] = f32x4{0.f, 0.f, 0.f, 0.f};
        acc[i][1] = f32x4{0.f, 0.f, 0.f, 0.f};
      }

      auto loadA = [&](int kk, f16x8* dst) {
        int kc = kbeg + kk * 32;
        const f16* ap; int ld;
        if (kc < 512) { ap = A0 + kc + ksub; ld = 512; }
        else          { ap = A1 + (kc - 512) + ksub; ld = 1024; }
#pragma unroll
        for (int rf = 0; rf < 4; ++rf)
          dst[rf] = *(const f16x8*)(ap + (size_t)(rf * 16 + l15) * ld);
      };

      f16x8 af[2][4];
      loadA(0, af[0]);
#pragma unroll
      for (int kk = 0; kk < 6; ++kk) {
        if (kk + 1 < 6) loadA(kk + 1, af[(kk + 1) & 1]);
#pragma unroll
        for (int rf = 0; rf < 4; ++rf) {
          acc[rf][0] = MFMA16(af[kk & 1][rf], wreg[kk][0], acc[rf][0]);
          acc[rf][1] = MFMA16(af[kk & 1][rf], wreg[kk][1], acc[rf][1]);
        }
      }

#pragma unroll
      for (int rf = 0; rf < 4; ++rf)
#pragma unroll
        for (int cf = 0; cf < 2; ++cf)
#pragma unroll
          for (int r = 0; r < 4; ++r)
            cred[w][rf * 16 + (lane >> 4) * 4 + r][cf * 16 + l15] = acc[rf][cf][r];
      __syncthreads();

      float ip = bI, fp = bF, gp = bG, op = bO;
#pragma unroll
      for (int ww = 0; ww < 8; ++ww) {
        ip += cred[ww][m][jl];
        fp += cred[ww][m][8 + jl];
        gp += cred[ww][m][16 + jl];
        op += cred[ww][m][24 + jl];
      }
      float ig = 1.f / (1.f + __expf(-ip));
      float fg = 1.f / (1.f + __expf(-fp));
      float gg = tanhf(gp);
      float og = 1.f / (1.f + __expf(-op));
      creg = fg * creg + ig * gg;
      float h = og * tanhf(creg);
      hout[(size_t)m * 1024 + jg] = (f16)h;

      __threadfence();  // release: drain h stores to coherence point
      __syncthreads();
      if (tid == 0)
        __hip_atomic_fetch_add(&sem0[t], 1, __ATOMIC_RELAXED, __HIP_MEMORY_SCOPE_AGENT);
    }
  } else {
    const f16* Bs = W1r + (size_t)jb * 32 * 2048;
    const int kbeg = w * 256;
    f16x8 wreg[8][2];
#pragma unroll
    for (int kk = 0; kk < 8; ++kk)
#pragma unroll
      for (int cf = 0; cf < 2; ++cf)
        wreg[kk][cf] = *(const f16x8*)(Bs + (size_t)(cf * 16 + l15) * 2048 + (kbeg + kk * 32 + ksub));

    for (int t = 0; t < 512; ++t) {
      if (tid == 0) {
        while (__hip_atomic_load(&sem0[t], __ATOMIC_RELAXED, __HIP_MEMORY_SCOPE_AGENT) < 128)
          __builtin_amdgcn_s_sleep(1);
        if (t >= 1)
          while (__hip_atomic_load(&sem1[t - 1], __ATOMIC_RELAXED, __HIP_MEMORY_SCOPE_AGENT) < 128)
            __builtin_amdgcn_s_sleep(1);
      }
      __syncthreads();
      __threadfence();

      const f16* A0 = (t & 1) ? h0b1 : h0b0;   // h0_t
      const f16* A1 = (t & 1) ? h1b0 : h1b1;   // h1_{t-1}
      f16* hout = (t & 1) ? h1b1 : h1b0;       // h1_t
      f16* hall = h1all + (size_t)t * 65536;

      f32x4 acc[4][2];
#pragma unroll
      for (int i = 0; i < 4; ++i) {
        acc[i][0] = f32x4{0.f, 0.f, 0.f, 0.f};
        acc[i][1] = f32x4{0.f, 0.f, 0.f, 0.f};
      }

      auto loadA = [&](int kk, f16x8* dst) {
        int kc = kbeg + kk * 32;
        const f16* ap;
        if (kc < 1024) { ap = A0 + kc + ksub; }
        else           { ap = A1 + (kc - 1024) + ksub; }
#pragma unroll
        for (int rf = 0; rf < 4; ++rf)
          dst[rf] = *(const f16x8*)(ap + (size_t)(rf * 16 + l15) * 1024);
      };

      f16x8 af[2][4];
      loadA(0, af[0]);
#pragma unroll
      for (int kk = 0; kk < 8; ++kk) {
        if (kk + 1 < 8) loadA(kk + 1, af[(kk + 1) & 1]);
#pragma unroll
        for (int rf = 0; rf < 4; ++rf) {
          acc[rf][0] = MFMA16(af[kk & 1][rf], wreg[kk][0], acc[rf][0]);
          acc[rf][1] = MFMA16(af[kk & 1][rf], wreg[kk][1], acc[rf][1]);
        }
      }

#pragma unroll
      for (int rf = 0; rf < 4; ++rf)
#pragma unroll
        for (int cf = 0; cf < 2; ++cf)
#pragma unroll
          for (int r = 0; r < 4; ++r)
            cred[w][rf * 16 + (lane >> 4) * 4 + r][cf * 16 + l15] = acc[rf][cf][r];
      __syncthreads();

      float ip = bI, fp = bF, gp = bG, op = bO;
#pragma unroll
      for (int ww = 0; ww < 8; ++ww) {
        ip += cred[ww][m][jl];
        fp += cred[ww][m][8 + jl];
        gp += cred[ww][m][16 + jl];
        op += cred[ww][m][24 + jl];
      }
      float ig = 1.f / (1.f + __expf(-ip));
      float fg = 1.f / (1.f + __expf(-fp));
      float gg = tanhf(gp);
      float og = 1.f / (1.f + __expf(-op));
      creg = fg * creg + ig * gg;
      float h = og * tanhf(creg);
      hout[(size_t)m * 1024 + jg] = (f16)h;
      hall[(size_t)m * 1024 + jg] = (f16)h;

      __threadfence();
      __syncthreads();
      if (tid == 0)
        __hip_atomic_fetch_add(&sem1[t], 1, __ATOMIC_RELAXED, __HIP_MEMORY_SCOPE_AGENT);
    }
  }
}

// ---------------- final FC ----------------
__global__ __launch_bounds__(512, 1)
void k_fc(const f16* __restrict__ h1all, const f16* __restrict__ Wfc16,
          const float* __restrict__ bfc, float* __restrict__ out) {
  const int s = blockIdx.x;
  const f16* A = h1all + (size_t)s * 65536;
  __shared__ float cred[8][64][65];

  const int w = threadIdx.x >> 6;
  const int lane = threadIdx.x & 63;
  const int l15 = lane & 15;
  const int ksub = (lane >> 4) << 3;

  f32x4 acc[4][4];
#pragma unroll
  for (int i = 0; i < 4; ++i)
#pragma unroll
    for (int j = 0; j < 4; ++j) acc[i][j] = f32x4{0.f, 0.f, 0.f, 0.f};

  const int kbeg = w * 128, kend = kbeg + 128;
  f16x8 af0[4], bf0[4], af1[4], bf1[4];

  auto LOADK = [&](int kc, f16x8(&a)[4], f16x8(&b)[4]) {
    const f16* ap = A + kc + ksub;
#pragma unroll
    for (int rf = 0; rf < 4; ++rf)
      a[rf] = *(const f16x8*)(ap + (size_t)(rf * 16 + l15) * 1024);
    const f16* bp = Wfc16 + kc + ksub;
#pragma unroll
    for (int cf = 0; cf < 4; ++cf)
      b[cf] = *(const f16x8*)(bp + (size_t)(cf * 16 + l15) * 1024);
  };

  LOADK(kbeg, af0, bf0);
  for (int kc = kbeg; kc < kend; kc += 64) {
    LOADK(kc + 32, af1, bf1);
#pragma unroll
    for (int rf = 0; rf < 4; ++rf)
#pragma unroll
      for (int cf = 0; cf < 4; ++cf) acc[rf][cf] = MFMA16(af0[rf], bf0[cf], acc[rf][cf]);
    if (kc + 64 < kend) LOADK(kc + 64, af0, bf0);
#pragma unroll
    for (int rf = 0; rf < 4; ++rf)
#pragma unroll
      for (int cf = 0; cf < 4; ++cf) acc[rf][cf] = MFMA16(af1[rf], bf1[cf], acc[rf][cf]);
  }

#pragma unroll
  for (int rf = 0; rf < 4; ++rf)
#pragma unroll
    for (int cf = 0; cf < 4; ++cf)
#pragma unroll
      for (int r = 0; r < 4; ++r)
        cred[w][rf * 16 + (lane >> 4) * 4 + r][cf * 16 + l15] = acc[rf][cf][r];

  __syncthreads();

  int m = threadIdx.x >> 3;
  int cbase = (threadIdx.x & 7) * 8;
#pragma unroll
  for (int u = 0; u < 8; ++u) {
    int col = cbase + u;
    float v = bfc[col];
#pragma unroll
    for (int ww = 0; ww < 8; ++ww) v += cred[ww][m][col];
    out[((size_t)m * 512 + s) * 64 + col] = v;
  }
}

// ---------------- host ----------------
extern "C" void kernel_launch(void* const* d_in, const int* in_sizes, int n_in,
                              void* d_out, int out_size, void* d_ws, size_t ws_size,
                              hipStream_t stream) {
  const float* x    = (const float*)d_in[0];
  const float* Wih0 = (const float*)d_in[1];
  const float* Whh0 = (const float*)d_in[2];
  const float* bih0 = (const float*)d_in[3];
  const float* bhh0 = (const float*)d_in[4];
  const float* Wih1 = (const float*)d_in[5];
  const float* Whh1 = (const float*)d_in[6];
  const float* bih1 = (const float*)d_in[7];
  const float* bhh1 = (const float*)d_in[8];
  const float* Wfc  = (const float*)d_in[9];
  const float* bfc  = (const float*)d_in[10];
  float* out = (float*)d_out;

  char* ws = (char*)d_ws;
  f16*   W0r   = (f16*)(ws + 0);           // 12,582,912
  f16*   W1r   = (f16*)(ws + 12582912);    // 16,777,216
  f16*   Wfc16 = (f16*)(ws + 29360128);    // 131,072
  float* b0r   = (float*)(ws + 29491200);  // 16,384
  float* b1r   = (float*)(ws + 29507584);  // 16,384
  f16*   x16   = (f16*)(ws + 29523968);    // 33,554,432
  f16*   h1all = (f16*)(ws + 63078400);    // 67,108,864
  f16*   h0b0  = (f16*)(ws + 130187264);   // 131,072
  f16*   h0b1  = (f16*)(ws + 130318336);   // 131,072
  f16*   h1b0  = (f16*)(ws + 130449408);   // 131,072
  f16*   h1b1  = (f16*)(ws + 130580480);   // 131,072
  int*   sem0  = (int*)(ws + 130711552);   // 2,048
  int*   sem1  = (int*)(ws + 130713600);   // 2,048

  k_conv_x<<<32768, 128, 0, stream>>>(x, x16);
  k_conv_w<<<4096, 256, 0, stream>>>(Wih0, Whh0, bih0, bhh0, W0r, b0r, 512);
  k_conv_w<<<4096, 256, 0, stream>>>(Wih1, Whh1, bih1, bhh1, W1r, b1r, 1024);
  k_conv_wfc<<<256, 256, 0, stream>>>(Wfc, Wfc16);
  // zero h double-buffers + semaphores (re-zeroed every launch: determinism)
  hipMemsetAsync(ws + 130187264, 0, 528384, stream);

  {
    const f16* x16c = x16; const f16* W0rc = W0r; const float* b0rc = b0r;
    const f16* W1rc = W1r; const float* b1rc = b1r;
    f16 *p0 = h0b0, *p1 = h0b1, *p2 = h1b0, *p3 = h1b1, *ph = h1all;
    int *s0 = sem0, *s1 = sem1;
    void* kargs[] = { &x16c, &W0rc, &b0rc, &W1rc, &b1rc,
                      &p0, &p1, &p2, &p3, &ph, &s0, &s1 };
    hipLaunchCooperativeKernel((void*)k_persist, dim3(256), dim3(512), kargs, 0, stream);
  }

  k_fc<<<512, 512, 0, stream>>>(h1all, Wfc16, bfc, out);
}

// Round 3
// 16000.420 us; speedup vs baseline: 2.9576x; 2.9576x over previous
//
#include <hip/hip_runtime.h>
#include <stdint.h>

typedef _Float16 f16;
typedef _Float16 f16x8 __attribute__((ext_vector_type(8)));
typedef float f32x4 __attribute__((ext_vector_type(4)));

#define MFMA16(a, b, c) __builtin_amdgcn_mfma_f32_16x16x32_f16((a), (b), (c), 0, 0, 0)

// Sizes: B=64, S=512, I=512, H=1024, 4H=4096, O=64

// ---------------- prep kernels ----------------

// x (B,S,I) f32 -> x16 (S,B,I) f16
__global__ void k_conv_x(const float* __restrict__ x, f16* __restrict__ x16) {
  int s = blockIdx.x >> 6, b = blockIdx.x & 63;
  const float4* src = (const float4*)(x + ((size_t)b * 512 + s) * 512);
  f16* dst = x16 + (size_t)blockIdx.x * 512;
  int tid = threadIdx.x;
  float4 v = src[tid];
  union { f16 h[4]; uint64_t u; } tmp;
  tmp.h[0] = (f16)v.x; tmp.h[1] = (f16)v.y; tmp.h[2] = (f16)v.z; tmp.h[3] = (f16)v.w;
  *(uint64_t*)(dst + tid * 4) = tmp.u;
}

// Weight reorder + f32->f16. Dest row d: jb=d>>5, r=d&31, q=r>>3, jl=r&7,
// source gate row g = q*1024 + jb*8 + jl. Row = [Wih(g,:) | Whh(g,:)].
__global__ void k_conv_w(const float* __restrict__ Wih, const float* __restrict__ Whh,
                         const float* __restrict__ bih, const float* __restrict__ bhh,
                         f16* __restrict__ Wr, float* __restrict__ br, int KI) {
  int d = blockIdx.x;
  int jb = d >> 5, r = d & 31, q = r >> 3, jl = r & 7;
  int g = q * 1024 + jb * 8 + jl;
  int Ktot = KI + 1024;
  const float* src0 = Wih + (size_t)g * KI;
  const float* src1 = Whh + (size_t)g * 1024;
  f16* dst = Wr + (size_t)d * Ktot;
  for (int k = threadIdx.x; k < Ktot; k += blockDim.x) {
    float v = (k < KI) ? src0[k] : src1[k - KI];
    dst[k] = (f16)v;
  }
  if (threadIdx.x == 0) br[d] = bih[g] + bhh[g];
}

__global__ void k_conv_wfc(const float* __restrict__ Wfc, f16* __restrict__ Wfc16) {
  int i = blockIdx.x * 256 + threadIdx.x;
  Wfc16[i] = (f16)Wfc[i];
}

// ---------------- persistent pipelined LSTM ----------------
// 256 blocks x 512 threads, cooperative. Blocks 0..127: layer0 slab jb.
// Blocks 128..255: layer1 slab jb. Weights pinned in VGPRs.
// Sync: per-block flags on separate 128B lines. flagL[j] = t+1 once block j of
// layer L finished step t. Consumers poll 128 flags in PARALLEL (one thread
// per flag, relaxed agent loads), then a single acquire fence per step.
// Producer: __syncthreads (drains h stores to L2) -> release fence (wbl2)
// -> relaxed flag store. No contended RMWs anywhere.
__global__ __launch_bounds__(512, 2)
void k_persist(const f16* __restrict__ x16,
               const f16* __restrict__ W0r, const float* __restrict__ b0r,
               const f16* __restrict__ W1r, const float* __restrict__ b1r,
               f16* __restrict__ h0b0, f16* __restrict__ h0b1,
               f16* __restrict__ h1b0, f16* __restrict__ h1b1,
               f16* __restrict__ h1all, int* flags) {
  const int layer = blockIdx.x >> 7;
  const int jb = blockIdx.x & 127;
  __shared__ float cred[8][64][36];  // stride 36: write 2-way, gate-read <=3-way

  int* flag0 = flags;               // [128] spaced by 32 ints (128B)
  int* flag1 = flags + 4096;
  int* myflag = (layer ? flag1 : flag0) + jb * 32;

  const int tid = threadIdx.x;
  const int w = tid >> 6, lane = tid & 63;
  const int l15 = lane & 15, ksub = (lane >> 4) << 3;
  const int m = tid >> 3, jl = tid & 7, jg = jb * 8 + jl;

  const float* bias = (layer ? b1r : b0r) + jb * 32;
  const float bI = bias[jl], bF = bias[8 + jl], bG = bias[16 + jl], bO = bias[24 + jl];
  float creg = 0.f;

  // poll target pointer for this thread (or null)
  const int* pollp = nullptr;
  int pollbase = 0;  // need = t + pollbase (skip if <= 0)
  if (tid < 128)      { pollp = flag0 + tid * 32;        pollbase = layer ? 1 : 0; }
  else if (tid < 256) { pollp = flag1 + (tid - 128) * 32; pollbase = layer ? 0 : -1; }

  if (layer == 0) {
    const f16* Bs = W0r + (size_t)jb * 32 * 1536;
    const int kbeg = w * 192;
    f16x8 wreg[6][2];
#pragma unroll
    for (int kk = 0; kk < 6; ++kk)
#pragma unroll
      for (int cf = 0; cf < 2; ++cf)
        wreg[kk][cf] = *(const f16x8*)(Bs + (size_t)(cf * 16 + l15) * 1536 + (kbeg + kk * 32 + ksub));
    // pin weights in VGPRs (stop the compiler from sinking the loads into the loop)
#pragma unroll
    for (int kk = 0; kk < 6; ++kk)
      asm volatile("" : "+v"(wreg[kk][0]), "+v"(wreg[kk][1]));

    for (int t = 0; t < 512; ++t) {
      {
        int need = t + pollbase;
        if (pollp && need > 0)
          while (__hip_atomic_load(pollp, __ATOMIC_RELAXED, __HIP_MEMORY_SCOPE_AGENT) < need)
            __builtin_amdgcn_s_sleep(1);
      }
      __syncthreads();
      __builtin_amdgcn_fence(__ATOMIC_ACQUIRE, "agent");  // inv L1/L2 (weights are in VGPRs)

      const f16* A0 = x16 + (size_t)t * 32768;
      const f16* A1 = (t & 1) ? h0b0 : h0b1;   // h0_{t-1}
      f16* hout = (t & 1) ? h0b1 : h0b0;       // h0_t

      f32x4 acc[4][2];
#pragma unroll
      for (int i = 0; i < 4; ++i) {
        acc[i][0] = f32x4{0.f, 0.f, 0.f, 0.f};
        acc[i][1] = f32x4{0.f, 0.f, 0.f, 0.f};
      }

      auto loadA = [&](int kk, f16x8* dst) {
        int kc = kbeg + kk * 32;
        const f16* ap; int ld;
        if (kc < 512) { ap = A0 + kc + ksub; ld = 512; }
        else          { ap = A1 + (kc - 512) + ksub; ld = 1024; }
#pragma unroll
        for (int rf = 0; rf < 4; ++rf)
          dst[rf] = *(const f16x8*)(ap + (size_t)(rf * 16 + l15) * ld);
      };

      f16x8 af[2][4];
      loadA(0, af[0]);
#pragma unroll
      for (int kk = 0; kk < 6; ++kk) {
        if (kk + 1 < 6) loadA(kk + 1, af[(kk + 1) & 1]);
#pragma unroll
        for (int rf = 0; rf < 4; ++rf) {
          acc[rf][0] = MFMA16(af[kk & 1][rf], wreg[kk][0], acc[rf][0]);
          acc[rf][1] = MFMA16(af[kk & 1][rf], wreg[kk][1], acc[rf][1]);
        }
      }

#pragma unroll
      for (int rf = 0; rf < 4; ++rf)
#pragma unroll
        for (int cf = 0; cf < 2; ++cf)
#pragma unroll
          for (int r = 0; r < 4; ++r)
            cred[w][rf * 16 + (lane >> 4) * 4 + r][cf * 16 + l15] = acc[rf][cf][r];
      __syncthreads();

      float ip = bI, fp = bF, gp = bG, op = bO;
#pragma unroll
      for (int ww = 0; ww < 8; ++ww) {
        ip += cred[ww][m][jl];
        fp += cred[ww][m][8 + jl];
        gp += cred[ww][m][16 + jl];
        op += cred[ww][m][24 + jl];
      }
      float ig = 1.f / (1.f + __expf(-ip));
      float fg = 1.f / (1.f + __expf(-fp));
      float gg = tanhf(gp);
      float og = 1.f / (1.f + __expf(-op));
      creg = fg * creg + ig * gg;
      float h = og * tanhf(creg);
      hout[(size_t)m * 1024 + jg] = (f16)h;

      __syncthreads();  // drains all waves' h stores to L2 (vmcnt0 before barrier)
      if (tid == 0) {
        __builtin_amdgcn_fence(__ATOMIC_RELEASE, "agent");  // wbl2: h visible at LLC
        __hip_atomic_store(myflag, t + 1, __ATOMIC_RELAXED, __HIP_MEMORY_SCOPE_AGENT);
      }
    }
  } else {
    const f16* Bs = W1r + (size_t)jb * 32 * 2048;
    const int kbeg = w * 256;
    f16x8 wreg[8][2];
#pragma unroll
    for (int kk = 0; kk < 8; ++kk)
#pragma unroll
      for (int cf = 0; cf < 2; ++cf)
        wreg[kk][cf] = *(const f16x8*)(Bs + (size_t)(cf * 16 + l15) * 2048 + (kbeg + kk * 32 + ksub));
#pragma unroll
    for (int kk = 0; kk < 8; ++kk)
      asm volatile("" : "+v"(wreg[kk][0]), "+v"(wreg[kk][1]));

    for (int t = 0; t < 512; ++t) {
      {
        int need = t + pollbase;
        if (pollp && need > 0)
          while (__hip_atomic_load(pollp, __ATOMIC_RELAXED, __HIP_MEMORY_SCOPE_AGENT) < need)
            __builtin_amdgcn_s_sleep(1);
      }
      __syncthreads();
      __builtin_amdgcn_fence(__ATOMIC_ACQUIRE, "agent");

      const f16* A0 = (t & 1) ? h0b1 : h0b0;   // h0_t
      const f16* A1 = (t & 1) ? h1b0 : h1b1;   // h1_{t-1}
      f16* hout = (t & 1) ? h1b1 : h1b0;       // h1_t
      f16* hall = h1all + (size_t)t * 65536;

      f32x4 acc[4][2];
#pragma unroll
      for (int i = 0; i < 4; ++i) {
        acc[i][0] = f32x4{0.f, 0.f, 0.f, 0.f};
        acc[i][1] = f32x4{0.f, 0.f, 0.f, 0.f};
      }

      auto loadA = [&](int kk, f16x8* dst) {
        int kc = kbeg + kk * 32;
        const f16* ap;
        if (kc < 1024) { ap = A0 + kc + ksub; }
        else           { ap = A1 + (kc - 1024) + ksub; }
#pragma unroll
        for (int rf = 0; rf < 4; ++rf)
          dst[rf] = *(const f16x8*)(ap + (size_t)(rf * 16 + l15) * 1024);
      };

      f16x8 af[2][4];
      loadA(0, af[0]);
#pragma unroll
      for (int kk = 0; kk < 8; ++kk) {
        if (kk + 1 < 8) loadA(kk + 1, af[(kk + 1) & 1]);
#pragma unroll
        for (int rf = 0; rf < 4; ++rf) {
          acc[rf][0] = MFMA16(af[kk & 1][rf], wreg[kk][0], acc[rf][0]);
          acc[rf][1] = MFMA16(af[kk & 1][rf], wreg[kk][1], acc[rf][1]);
        }
      }

#pragma unroll
      for (int rf = 0; rf < 4; ++rf)
#pragma unroll
        for (int cf = 0; cf < 2; ++cf)
#pragma unroll
          for (int r = 0; r < 4; ++r)
            cred[w][rf * 16 + (lane >> 4) * 4 + r][cf * 16 + l15] = acc[rf][cf][r];
      __syncthreads();

      float ip = bI, fp = bF, gp = bG, op = bO;
#pragma unroll
      for (int ww = 0; ww < 8; ++ww) {
        ip += cred[ww][m][jl];
        fp += cred[ww][m][8 + jl];
        gp += cred[ww][m][16 + jl];
        op += cred[ww][m][24 + jl];
      }
      float ig = 1.f / (1.f + __expf(-ip));
      float fg = 1.f / (1.f + __expf(-fp));
      float gg = tanhf(gp);
      float og = 1.f / (1.f + __expf(-op));
      creg = fg * creg + ig * gg;
      float h = og * tanhf(creg);
      hout[(size_t)m * 1024 + jg] = (f16)h;
      hall[(size_t)m * 1024 + jg] = (f16)h;

      __syncthreads();
      if (tid == 0) {
        __builtin_amdgcn_fence(__ATOMIC_RELEASE, "agent");
        __hip_atomic_store(myflag, t + 1, __ATOMIC_RELAXED, __HIP_MEMORY_SCOPE_AGENT);
      }
    }
  }
}

// ---------------- final FC ----------------
__global__ __launch_bounds__(512, 1)
void k_fc(const f16* __restrict__ h1all, const f16* __restrict__ Wfc16,
          const float* __restrict__ bfc, float* __restrict__ out) {
  const int s = blockIdx.x;
  const f16* A = h1all + (size_t)s * 65536;
  __shared__ float cred[8][64][68];

  const int w = threadIdx.x >> 6;
  const int lane = threadIdx.x & 63;
  const int l15 = lane & 15;
  const int ksub = (lane >> 4) << 3;

  f32x4 acc[4][4];
#pragma unroll
  for (int i = 0; i < 4; ++i)
#pragma unroll
    for (int j = 0; j < 4; ++j) acc[i][j] = f32x4{0.f, 0.f, 0.f, 0.f};

  const int kbeg = w * 128, kend = kbeg + 128;
  f16x8 af0[4], bf0[4], af1[4], bf1[4];

  auto LOADK = [&](int kc, f16x8(&a)[4], f16x8(&b)[4]) {
    const f16* ap = A + kc + ksub;
#pragma unroll
    for (int rf = 0; rf < 4; ++rf)
      a[rf] = *(const f16x8*)(ap + (size_t)(rf * 16 + l15) * 1024);
    const f16* bp = Wfc16 + kc + ksub;
#pragma unroll
    for (int cf = 0; cf < 4; ++cf)
      b[cf] = *(const f16x8*)(bp + (size_t)(cf * 16 + l15) * 1024);
  };

  LOADK(kbeg, af0, bf0);
  for (int kc = kbeg; kc < kend; kc += 64) {
    LOADK(kc + 32, af1, bf1);
#pragma unroll
    for (int rf = 0; rf < 4; ++rf)
#pragma unroll
      for (int cf = 0; cf < 4; ++cf) acc[rf][cf] = MFMA16(af0[rf], bf0[cf], acc[rf][cf]);
    if (kc + 64 < kend) LOADK(kc + 64, af0, bf0);
#pragma unroll
    for (int rf = 0; rf < 4; ++rf)
#pragma unroll
      for (int cf = 0; cf < 4; ++cf) acc[rf][cf] = MFMA16(af1[rf], bf1[cf], acc[rf][cf]);
  }

#pragma unroll
  for (int rf = 0; rf < 4; ++rf)
#pragma unroll
    for (int cf = 0; cf < 4; ++cf)
#pragma unroll
      for (int r = 0; r < 4; ++r)
        cred[w][rf * 16 + (lane >> 4) * 4 + r][cf * 16 + l15] = acc[rf][cf][r];

  __syncthreads();

  int m = threadIdx.x >> 3;
  int cbase = (threadIdx.x & 7) * 8;
#pragma unroll
  for (int u = 0; u < 8; ++u) {
    int col = cbase + u;
    float v = bfc[col];
#pragma unroll
    for (int ww = 0; ww < 8; ++ww) v += cred[ww][m][col];
    out[((size_t)m * 512 + s) * 64 + col] = v;
  }
}

// ---------------- host ----------------
extern "C" void kernel_launch(void* const* d_in, const int* in_sizes, int n_in,
                              void* d_out, int out_size, void* d_ws, size_t ws_size,
                              hipStream_t stream) {
  const float* x    = (const float*)d_in[0];
  const float* Wih0 = (const float*)d_in[1];
  const float* Whh0 = (const float*)d_in[2];
  const float* bih0 = (const float*)d_in[3];
  const float* bhh0 = (const float*)d_in[4];
  const float* Wih1 = (const float*)d_in[5];
  const float* Whh1 = (const float*)d_in[6];
  const float* bih1 = (const float*)d_in[7];
  const float* bhh1 = (const float*)d_in[8];
  const float* Wfc  = (const float*)d_in[9];
  const float* bfc  = (const float*)d_in[10];
  float* out = (float*)d_out;

  char* ws = (char*)d_ws;
  f16*   W0r   = (f16*)(ws + 0);           // 12,582,912
  f16*   W1r   = (f16*)(ws + 12582912);    // 16,777,216
  f16*   Wfc16 = (f16*)(ws + 29360128);    // 131,072
  float* b0r   = (float*)(ws + 29491200);  // 16,384
  float* b1r   = (float*)(ws + 29507584);  // 16,384
  f16*   x16   = (f16*)(ws + 29523968);    // 33,554,432
  f16*   h1all = (f16*)(ws + 63078400);    // 67,108,864
  f16*   h0b0  = (f16*)(ws + 130187264);   // 131,072
  f16*   h0b1  = (f16*)(ws + 130318336);   // 131,072
  f16*   h1b0  = (f16*)(ws + 130449408);   // 131,072
  f16*   h1b1  = (f16*)(ws + 130580480);   // 131,072
  int*   flags = (int*)(ws + 130711552);   // 2*128*128B = 32,768

  k_conv_x<<<32768, 128, 0, stream>>>(x, x16);
  k_conv_w<<<4096, 256, 0, stream>>>(Wih0, Whh0, bih0, bhh0, W0r, b0r, 512);
  k_conv_w<<<4096, 256, 0, stream>>>(Wih1, Whh1, bih1, bhh1, W1r, b1r, 1024);
  k_conv_wfc<<<256, 256, 0, stream>>>(Wfc, Wfc16);
  // zero h double-buffers + flags every launch (determinism under graph replay)
  hipMemsetAsync(ws + 130187264, 0, 524288 + 32768, stream);

  {
    const f16* x16c = x16; const f16* W0rc = W0r; const float* b0rc = b0r;
    const f16* W1rc = W1r; const float* b1rc = b1r;
    f16 *p0 = h0b0, *p1 = h0b1, *p2 = h1b0, *p3 = h1b1, *ph = h1all;
    int* fl = flags;
    void* kargs[] = { &x16c, &W0rc, &b0rc, &W1rc, &b1rc,
                      &p0, &p1, &p2, &p3, &ph, &fl };
    hipLaunchCooperativeKernel((void*)k_persist, dim3(256), dim3(512), kargs, 0, stream);
  }

  k_fc<<<512, 512, 0, stream>>>(h1all, Wfc16, bfc, out);
}

// Round 4
// 15415.422 us; speedup vs baseline: 3.0698x; 1.0379x over previous
//
#include <hip/hip_runtime.h>
#include <stdint.h>

typedef _Float16 f16;
typedef _Float16 f16x8 __attribute__((ext_vector_type(8)));
typedef float f32x4 __attribute__((ext_vector_type(4)));

#define MFMA16(a, b, c) __builtin_amdgcn_mfma_f32_16x16x32_f16((a), (b), (c), 0, 0, 0)

// Sizes: B=64, S=512, I=512, H=1024, 4H=4096, O=64

// ---------------- prep kernels ----------------

// x (B,S,I) f32 -> x16 (S,B,I) f16
__global__ void k_conv_x(const float* __restrict__ x, f16* __restrict__ x16) {
  int s = blockIdx.x >> 6, b = blockIdx.x & 63;
  const float4* src = (const float4*)(x + ((size_t)b * 512 + s) * 512);
  f16* dst = x16 + (size_t)blockIdx.x * 512;
  int tid = threadIdx.x;
  float4 v = src[tid];
  union { f16 h[4]; uint64_t u; } tmp;
  tmp.h[0] = (f16)v.x; tmp.h[1] = (f16)v.y; tmp.h[2] = (f16)v.z; tmp.h[3] = (f16)v.w;
  *(uint64_t*)(dst + tid * 4) = tmp.u;
}

// Weights -> MFMA B-fragment order, f32->f16.
// frag id fid = (jb*8 + w)*KK + kk;  lane holds W[c][k..k+7] where
// c = (w>>2)*16 + (lane&15) (slab col), k = (w&3)*K4 + kk*32 + (lane>>4)*8.
// slab col r -> source gate row g = (r>>3)*1024 + jb*8 + (r&7).
__global__ void k_conv_wfrag(const float* __restrict__ Wih, const float* __restrict__ Whh,
                             f16* __restrict__ Wf, int KI, int KK, int K4) {
  int fid = blockIdx.x;
  int lane = threadIdx.x;
  int kk = fid % KK; int rest = fid / KK; int w = rest & 7; int jb = rest >> 3;
  int r = (w >> 2) * 16 + (lane & 15);
  int g = (r >> 3) * 1024 + jb * 8 + (r & 7);
  int k = (w & 3) * K4 + kk * 32 + ((lane >> 4) << 3);
  const float* src = (k < KI) ? (Wih + (size_t)g * KI + k)
                              : (Whh + (size_t)g * 1024 + (k - KI));
  union { f16 h[8]; f16x8 v; } t;
#pragma unroll
  for (int i = 0; i < 8; ++i) t.h[i] = (f16)src[i];
  *(f16x8*)(Wf + ((size_t)fid * 64 + lane) * 8) = t.v;
}

__global__ void k_conv_bias(const float* __restrict__ bih, const float* __restrict__ bhh,
                            float* __restrict__ br) {
  int d = blockIdx.x * 64 + threadIdx.x;  // 4096
  int jb = d >> 5, r = d & 31;
  int g = (r >> 3) * 1024 + jb * 8 + (r & 7);
  br[d] = bih[g] + bhh[g];
}

__global__ void k_conv_wfc(const float* __restrict__ Wfc, f16* __restrict__ Wfc16) {
  int i = blockIdx.x * 256 + threadIdx.x;
  Wfc16[i] = (f16)Wfc[i];
}

// ---------------- persistent pipelined LSTM ----------------
// 256 blocks x 512 threads, cooperative. Blocks 0..127: layer0 slab jb,
// 128..255: layer1 slab jb. Weights in LDS (fragment-linear, conflict-free
// ds_read_b128); last k-fragment per wave in regs. h stores are sc0/sc1
// write-through (no release fence needed); one acquire-inv fence per step;
// per-wave parallel flag polling; 4-deep A-load pipeline.
__global__ __launch_bounds__(512, 2)
void k_persist(const f16* __restrict__ x16,
               const f16* __restrict__ W0f, const float* __restrict__ b0r,
               const f16* __restrict__ W1f, const float* __restrict__ b1r,
               f16* __restrict__ h0b0, f16* __restrict__ h0b1,
               f16* __restrict__ h1b0, f16* __restrict__ h1b1,
               f16* __restrict__ h1all, int* flags) {
  const int layer = blockIdx.x >> 7;
  const int jb = blockIdx.x & 127;

  __shared__ f16 wlds[61440];            // 8 waves * 15 frags * 1KB = 120KB max
  __shared__ float cred[2][4][64][17];   // 34.8KB; total 157.7KB < 160KB

  int* flag0 = flags;          // 128 flags, 128B apart
  int* flag1 = flags + 4096;
  int* myflag = (layer ? flag1 : flag0) + jb * 32;

  const int tid = threadIdx.x;
  const int w = tid >> 6, lane = tid & 63;
  const int l15 = lane & 15, q8 = (lane >> 4) << 3;
  const int cg = w >> 2, wg = w & 3;
  const int m = tid >> 3, jl = tid & 7, jg = jb * 8 + jl;

  const float* bias = (layer ? b1r : b0r) + jb * 32;
  const float bI = bias[jl], bF = bias[8 + jl], bG = bias[16 + jl], bO = bias[24 + jl];
  float creg = 0.f;

  const int* pf0a = flag0 + lane * 32;
  const int* pf0b = flag0 + (64 + lane) * 32;
  const int* pf1a = flag1 + lane * 32;
  const int* pf1b = flag1 + (64 + lane) * 32;

#define POLL(n0v, n1v)                                                                   \
  {                                                                                      \
    int n0 = (n0v), n1 = (n1v);                                                          \
    for (;;) {                                                                           \
      int a_ = __hip_atomic_load(pf0a, __ATOMIC_RELAXED, __HIP_MEMORY_SCOPE_AGENT);      \
      int b_ = __hip_atomic_load(pf0b, __ATOMIC_RELAXED, __HIP_MEMORY_SCOPE_AGENT);      \
      int c_ = __hip_atomic_load(pf1a, __ATOMIC_RELAXED, __HIP_MEMORY_SCOPE_AGENT);      \
      int d_ = __hip_atomic_load(pf1b, __ATOMIC_RELAXED, __HIP_MEMORY_SCOPE_AGENT);      \
      if (__all((a_ >= n0) && (b_ >= n0) && (c_ >= n1) && (d_ >= n1))) break;            \
      __builtin_amdgcn_s_sleep(2);                                                       \
    }                                                                                    \
  }

#define CRED_AND_POINTWISE(HOUT, HALL)                                                   \
  {                                                                                      \
    _Pragma("unroll") for (int rf = 0; rf < 4; ++rf)                                     \
      _Pragma("unroll") for (int r = 0; r < 4; ++r)                                      \
        cred[cg][wg][rf * 16 + (lane >> 4) * 4 + r][l15] = acc[rf][r];                   \
    __syncthreads();                                                                     \
    float ip = bI, fp = bF, gp = bG, op = bO;                                            \
    _Pragma("unroll") for (int u = 0; u < 4; ++u) {                                      \
      ip += cred[0][u][m][jl];                                                           \
      fp += cred[0][u][m][8 + jl];                                                       \
      gp += cred[1][u][m][jl];                                                           \
      op += cred[1][u][m][8 + jl];                                                       \
    }                                                                                    \
    float ig = 1.f / (1.f + __expf(-ip));                                                \
    float fg = 1.f / (1.f + __expf(-fp));                                                \
    float ea = __expf(-2.f * fabsf(gp));                                                 \
    float gg = copysignf((1.f - ea) / (1.f + ea), gp);                                   \
    float og = 1.f / (1.f + __expf(-op));                                                \
    creg = fg * creg + ig * gg;                                                          \
    float eb = __expf(-2.f * fabsf(creg));                                               \
    float hval = og * copysignf((1.f - eb) / (1.f + eb), creg);                          \
    union { f16 h; unsigned short u; } cv; cv.h = (f16)hval;                             \
    unsigned int hw = cv.u;                                                              \
    asm volatile("global_store_short %0, %1, off sc0 sc1" ::                             \
                 "v"((HOUT) + (size_t)m * 1024 + jg), "v"(hw) : "memory");               \
    if (HALL) {                                                                          \
      asm volatile("global_store_short %0, %1, off sc0 sc1" ::                           \
                   "v"((f16*)(HALL) + (size_t)m * 1024 + jg), "v"(hw) : "memory");       \
    }                                                                                    \
    asm volatile("s_waitcnt vmcnt(0)" ::: "memory");                                     \
    __syncthreads();                                                                     \
    if (tid == 0) {                                                                      \
      int fv = t + 1;                                                                    \
      asm volatile("global_store_dword %0, %1, off sc0 sc1" ::                           \
                   "v"(myflag), "v"(fv) : "memory");                                     \
    }                                                                                    \
  }

  if (layer == 0) {
    const int KK = 12;  // K4 = 384, Ktot = 1536
    const f16* Wfrag = W0f + (size_t)(jb * 8 + w) * KK * 512;
#pragma unroll
    for (int kk = 0; kk < KK - 1; ++kk)
      *(f16x8*)(wlds + ((size_t)(w * (KK - 1) + kk) * 64 + lane) * 8) =
          *(const f16x8*)(Wfrag + ((size_t)kk * 64 + lane) * 8);
    f16x8 wlast = *(const f16x8*)(Wfrag + ((size_t)(KK - 1) * 64 + lane) * 8);
    __syncthreads();

    const int kbeg = wg * 384;
    for (int t = 0; t < 512; ++t) {
      const f16* A0 = x16 + (size_t)t * 32768;
      const f16* A1 = (t & 1) ? h0b0 : h0b1;  // h0_{t-1}
      f16* hout = (t & 1) ? h0b1 : h0b0;      // h0_t

      f16x8 af[4][4];
      auto loadA = [&](int kk, int slot) {
        int k = kbeg + kk * 32 + q8;
        const f16* ap; int ld;
        if (k < 512) { ap = A0 + k; ld = 512; }
        else         { ap = A1 + (k - 512); ld = 1024; }
#pragma unroll
        for (int rf = 0; rf < 4; ++rf)
          af[slot][rf] = *(const f16x8*)(ap + (size_t)(rf * 16 + l15) * ld);
      };

      // waves 0-7 with wg<2 have pure-x K-slices for kk 0..3: flag-independent prefetch
      if (wg < 2) { loadA(0, 0); loadA(1, 1); loadA(2, 2); loadA(3, 3); }
      POLL(t, t - 1);
      __builtin_amdgcn_fence(__ATOMIC_ACQUIRE, "agent");
      if (wg >= 2) { loadA(0, 0); loadA(1, 1); loadA(2, 2); loadA(3, 3); }

      f32x4 acc[4];
#pragma unroll
      for (int i = 0; i < 4; ++i) acc[i] = f32x4{0.f, 0.f, 0.f, 0.f};

      f16x8 wkA = *(const f16x8*)(wlds + ((size_t)(w * 11 + 0) * 64 + lane) * 8);
      f16x8 wkB = *(const f16x8*)(wlds + ((size_t)(w * 11 + 1) * 64 + lane) * 8);
#pragma unroll
      for (int kk = 0; kk < 12; ++kk) {
        f16x8 cur = (kk & 1) ? wkB : wkA;
        if (kk + 2 < 12) {
          f16x8 nxt = (kk + 2 < 11)
              ? *(const f16x8*)(wlds + ((size_t)(w * 11 + kk + 2) * 64 + lane) * 8)
              : wlast;
          if (kk & 1) wkB = nxt; else wkA = nxt;
        }
#pragma unroll
        for (int rf = 0; rf < 4; ++rf)
          acc[rf] = MFMA16(af[kk & 3][rf], cur, acc[rf]);
        if (kk + 4 < 12) loadA(kk + 4, kk & 3);
      }

      CRED_AND_POINTWISE(hout, (f16*)nullptr);
    }
  } else {
    const int KK = 16;  // K4 = 512, Ktot = 2048
    const f16* Wfrag = W1f + (size_t)(jb * 8 + w) * KK * 512;
#pragma unroll
    for (int kk = 0; kk < KK - 1; ++kk)
      *(f16x8*)(wlds + ((size_t)(w * (KK - 1) + kk) * 64 + lane) * 8) =
          *(const f16x8*)(Wfrag + ((size_t)kk * 64 + lane) * 8);
    f16x8 wlast = *(const f16x8*)(Wfrag + ((size_t)(KK - 1) * 64 + lane) * 8);
    __syncthreads();

    const int kbeg = wg * 512;
    for (int t = 0; t < 512; ++t) {
      const f16* A0 = (t & 1) ? h0b1 : h0b0;  // h0_t
      const f16* A1 = (t & 1) ? h1b0 : h1b1;  // h1_{t-1}
      f16* hout = (t & 1) ? h1b1 : h1b0;      // h1_t
      f16* hall = h1all + (size_t)t * 65536;

      f16x8 af[4][4];
      auto loadA = [&](int kk, int slot) {
        int k = kbeg + kk * 32 + q8;
        const f16* ap = (k < 1024) ? (A0 + k) : (A1 + (k - 1024));
#pragma unroll
        for (int rf = 0; rf < 4; ++rf)
          af[slot][rf] = *(const f16x8*)(ap + (size_t)(rf * 16 + l15) * 1024);
      };

      POLL(t + 1, t);
      __builtin_amdgcn_fence(__ATOMIC_ACQUIRE, "agent");
      loadA(0, 0); loadA(1, 1); loadA(2, 2); loadA(3, 3);

      f32x4 acc[4];
#pragma unroll
      for (int i = 0; i < 4; ++i) acc[i] = f32x4{0.f, 0.f, 0.f, 0.f};

      f16x8 wkA = *(const f16x8*)(wlds + ((size_t)(w * 15 + 0) * 64 + lane) * 8);
      f16x8 wkB = *(const f16x8*)(wlds + ((size_t)(w * 15 + 1) * 64 + lane) * 8);
#pragma unroll
      for (int kk = 0; kk < 16; ++kk) {
        f16x8 cur = (kk & 1) ? wkB : wkA;
        if (kk + 2 < 16) {
          f16x8 nxt = (kk + 2 < 15)
              ? *(const f16x8*)(wlds + ((size_t)(w * 15 + kk + 2) * 64 + lane) * 8)
              : wlast;
          if (kk & 1) wkB = nxt; else wkA = nxt;
        }
#pragma unroll
        for (int rf = 0; rf < 4; ++rf)
          acc[rf] = MFMA16(af[kk & 3][rf], cur, acc[rf]);
        if (kk + 4 < 16) loadA(kk + 4, kk & 3);
      }

      CRED_AND_POINTWISE(hout, hall);
    }
  }
#undef POLL
#undef CRED_AND_POINTWISE
}

// ---------------- final FC ----------------
__global__ __launch_bounds__(512, 1)
void k_fc(const f16* __restrict__ h1all, const f16* __restrict__ Wfc16,
          const float* __restrict__ bfc, float* __restrict__ out) {
  const int s = blockIdx.x;
  const f16* A = h1all + (size_t)s * 65536;
  __shared__ float credf[8][64][68];

  const int w = threadIdx.x >> 6;
  const int lane = threadIdx.x & 63;
  const int l15 = lane & 15;
  const int ksub = (lane >> 4) << 3;

  f32x4 acc[4][4];
#pragma unroll
  for (int i = 0; i < 4; ++i)
#pragma unroll
    for (int j = 0; j < 4; ++j) acc[i][j] = f32x4{0.f, 0.f, 0.f, 0.f};

  const int kbeg = w * 128, kend = kbeg + 128;
  f16x8 af0[4], bf0[4], af1[4], bf1[4];

  auto LOADK = [&](int kc, f16x8(&a)[4], f16x8(&b)[4]) {
    const f16* ap = A + kc + ksub;
#pragma unroll
    for (int rf = 0; rf < 4; ++rf)
      a[rf] = *(const f16x8*)(ap + (size_t)(rf * 16 + l15) * 1024);
    const f16* bp = Wfc16 + kc + ksub;
#pragma unroll
    for (int cf = 0; cf < 4; ++cf)
      b[cf] = *(const f16x8*)(bp + (size_t)(cf * 16 + l15) * 1024);
  };

  LOADK(kbeg, af0, bf0);
  for (int kc = kbeg; kc < kend; kc += 64) {
    LOADK(kc + 32, af1, bf1);
#pragma unroll
    for (int rf = 0; rf < 4; ++rf)
#pragma unroll
      for (int cf = 0; cf < 4; ++cf) acc[rf][cf] = MFMA16(af0[rf], bf0[cf], acc[rf][cf]);
    if (kc + 64 < kend) LOADK(kc + 64, af0, bf0);
#pragma unroll
    for (int rf = 0; rf < 4; ++rf)
#pragma unroll
      for (int cf = 0; cf < 4; ++cf) acc[rf][cf] = MFMA16(af1[rf], bf1[cf], acc[rf][cf]);
  }

#pragma unroll
  for (int rf = 0; rf < 4; ++rf)
#pragma unroll
    for (int cf = 0; cf < 4; ++cf)
#pragma unroll
      for (int r = 0; r < 4; ++r)
        credf[w][rf * 16 + (lane >> 4) * 4 + r][cf * 16 + l15] = acc[rf][cf][r];

  __syncthreads();

  int m = threadIdx.x >> 3;
  int cbase = (threadIdx.x & 7) * 8;
#pragma unroll
  for (int u = 0; u < 8; ++u) {
    int col = cbase + u;
    float v = bfc[col];
#pragma unroll
    for (int ww = 0; ww < 8; ++ww) v += credf[ww][m][col];
    out[((size_t)m * 512 + s) * 64 + col] = v;
  }
}

// ---------------- host ----------------
extern "C" void kernel_launch(void* const* d_in, const int* in_sizes, int n_in,
                              void* d_out, int out_size, void* d_ws, size_t ws_size,
                              hipStream_t stream) {
  const float* x    = (const float*)d_in[0];
  const float* Wih0 = (const float*)d_in[1];
  const float* Whh0 = (const float*)d_in[2];
  const float* bih0 = (const float*)d_in[3];
  const float* bhh0 = (const float*)d_in[4];
  const float* Wih1 = (const float*)d_in[5];
  const float* Whh1 = (const float*)d_in[6];
  const float* bih1 = (const float*)d_in[7];
  const float* bhh1 = (const float*)d_in[8];
  const float* Wfc  = (const float*)d_in[9];
  const float* bfc  = (const float*)d_in[10];
  float* out = (float*)d_out;

  char* ws = (char*)d_ws;
  f16*   W0f   = (f16*)(ws + 0);           // 128*8*12 frags * 1KB = 12,582,912
  f16*   W1f   = (f16*)(ws + 12582912);    // 128*8*16 frags * 1KB = 16,777,216
  f16*   Wfc16 = (f16*)(ws + 29360128);    // 131,072
  float* b0r   = (float*)(ws + 29491200);  // 16,384
  float* b1r   = (float*)(ws + 29507584);  // 16,384
  f16*   x16   = (f16*)(ws + 29523968);    // 33,554,432
  f16*   h1all = (f16*)(ws + 63078400);    // 67,108,864
  f16*   h0b0  = (f16*)(ws + 130187264);   // 131,072
  f16*   h0b1  = (f16*)(ws + 130318336);   // 131,072
  f16*   h1b0  = (f16*)(ws + 130449408);   // 131,072
  f16*   h1b1  = (f16*)(ws + 130580480);   // 131,072
  int*   flags = (int*)(ws + 130711552);   // 32,768

  k_conv_x<<<32768, 128, 0, stream>>>(x, x16);
  k_conv_wfrag<<<12288, 64, 0, stream>>>(Wih0, Whh0, W0f, 512, 12, 384);
  k_conv_wfrag<<<16384, 64, 0, stream>>>(Wih1, Whh1, W1f, 1024, 16, 512);
  k_conv_bias<<<64, 64, 0, stream>>>(bih0, bhh0, b0r);
  k_conv_bias<<<64, 64, 0, stream>>>(bih1, bhh1, b1r);
  k_conv_wfc<<<256, 256, 0, stream>>>(Wfc, Wfc16);
  // zero h double-buffers + flags every launch (determinism under graph replay)
  hipMemsetAsync(ws + 130187264, 0, 524288 + 32768, stream);

  {
    const f16* x16c = x16; const f16* W0fc = W0f; const float* b0rc = b0r;
    const f16* W1fc = W1f; const float* b1rc = b1r;
    f16 *p0 = h0b0, *p1 = h0b1, *p2 = h1b0, *p3 = h1b1, *ph = h1all;
    int* fl = flags;
    void* kargs[] = { &x16c, &W0fc, &b0rc, &W1fc, &b1rc,
                      &p0, &p1, &p2, &p3, &ph, &fl };
    hipLaunchCooperativeKernel((void*)k_persist, dim3(256), dim3(512), kargs, 0, stream);
  }

  k_fc<<<512, 512, 0, stream>>>(h1all, Wfc16, bfc, out);
}

// Round 5
// 9250.233 us; speedup vs baseline: 5.1158x; 1.6665x over previous
//
#include <hip/hip_runtime.h>
#include <stdint.h>

typedef _Float16 f16;
typedef _Float16 f16x8 __attribute__((ext_vector_type(8)));
typedef float f32x4 __attribute__((ext_vector_type(4)));

#define MFMA16(a, b, c) __builtin_amdgcn_mfma_f32_16x16x32_f16((a), (b), (c), 0, 0, 0)

// Sizes: B=64, S=512, I=512, H=1024, 4H=4096, O=64

// ---------------- prep kernels ----------------

// x (B,S,I) f32 -> x16 (S,B,I) f16; flat, 8 elems/thread
__global__ void k_conv_x(const float* __restrict__ x, f16* __restrict__ x16) {
  int i = blockIdx.x * 256 + threadIdx.x;   // 2,097,152 threads
  int o = i * 8;
  int s = o >> 15, b = (o >> 9) & 63, c = o & 511;
  const float* src = x + (size_t)b * 262144 + (size_t)s * 512 + c;
  float4 v0 = *(const float4*)(src);
  float4 v1 = *(const float4*)(src + 4);
  union { f16 h[8]; f16x8 v; } t;
  t.h[0] = (f16)v0.x; t.h[1] = (f16)v0.y; t.h[2] = (f16)v0.z; t.h[3] = (f16)v0.w;
  t.h[4] = (f16)v1.x; t.h[5] = (f16)v1.y; t.h[6] = (f16)v1.z; t.h[7] = (f16)v1.w;
  *(f16x8*)(x16 + o) = t.v;
}

// Weights -> per-(slab,wave,kk,colhalf) MFMA B-fragments, f32->f16.
// fid = ((jb*8 + w)*KK + kk)*2 + cf. Lane holds W[c][k..k+7]:
//   slab col c = cf*16 + (lane&15)  -> gate row g = (c>>3)*1024 + jb*8 + (c&7)
//   k = w*kPer + kk*32 + (lane>>4)*8
__global__ void k_conv_wfrag(const float* __restrict__ Wih, const float* __restrict__ Whh,
                             f16* __restrict__ Wf, int KI, int KK, int kPer) {
  int fid = blockIdx.x;
  int lane = threadIdx.x;
  int cf = fid & 1; int rest = fid >> 1;
  int kk = rest % KK; rest /= KK; int w = rest & 7; int jb = rest >> 3;
  int c = cf * 16 + (lane & 15);
  int g = (c >> 3) * 1024 + jb * 8 + (c & 7);
  int k = w * kPer + kk * 32 + ((lane >> 4) << 3);
  const float* src = (k < KI) ? (Wih + (size_t)g * KI + k)
                              : (Whh + (size_t)g * 1024 + (k - KI));
  union { f16 h[8]; f16x8 v; } t;
#pragma unroll
  for (int i = 0; i < 8; ++i) t.h[i] = (f16)src[i];
  *(f16x8*)(Wf + ((size_t)fid * 64 + lane) * 8) = t.v;
}

__global__ void k_conv_bias(const float* __restrict__ bih, const float* __restrict__ bhh,
                            float* __restrict__ br) {
  int d = blockIdx.x * 64 + threadIdx.x;  // 4096
  int jb = d >> 5, r = d & 31;
  int g = (r >> 3) * 1024 + jb * 8 + (r & 7);
  br[d] = bih[g] + bhh[g];
}

__global__ void k_conv_wfc(const float* __restrict__ Wfc, f16* __restrict__ Wfc16) {
  int i = blockIdx.x * 256 + threadIdx.x;
  Wfc16[i] = (f16)Wfc[i];
}

// ---------------- persistent pipelined LSTM ----------------
// 256 blocks x 512 threads, cooperative. Blocks 0..127: layer0 slab jb,
// 128..255: layer1 slab jb. 8-way K-split, each wave computes 64x32 via
// acc[4][2]. h state: 4-deep ring buffers; ALL h traffic via relaxed
// agent-scope atomics (LLC-coherent by construction) -> NO fences, L2 never
// invalidated, x16/weights stay L2-hot forever.
__global__ __launch_bounds__(512, 2)
void k_persist(const f16* __restrict__ x16,
               const f16* __restrict__ W0f, const float* __restrict__ b0r,
               const f16* __restrict__ W1f, const float* __restrict__ b1r,
               f16* __restrict__ h0buf, f16* __restrict__ h1buf,
               f16* __restrict__ h1all, int* flags) {
  const int layer = blockIdx.x >> 7;
  const int jb = blockIdx.x & 127;

  __shared__ float cred[8][64][36];  // stride 36: write 2-way, gate-read 2-way

  int* flag0 = flags;          // 128 flags, 128B apart
  int* flag1 = flags + 4096;
  int* myflag = (layer ? flag1 : flag0) + jb * 32;

  const int tid = threadIdx.x;
  const int w = tid >> 6, lane = tid & 63;
  const int l15 = lane & 15, q8 = (lane >> 4) << 3;
  const int m = tid >> 3, jl = tid & 7, jg = jb * 8 + jl;

  const float* bias = (layer ? b1r : b0r) + jb * 32;
  const float bI = bias[jl], bF = bias[8 + jl], bG = bias[16 + jl], bO = bias[24 + jl];
  float creg = 0.f;

  const int* pf0a = flag0 + lane * 32;
  const int* pf0b = flag0 + (64 + lane) * 32;
  const int* pf1a = flag1 + lane * 32;
  const int* pf1b = flag1 + (64 + lane) * 32;

  union U16 { unsigned long long u[2]; f16x8 v; };

#define POLL(n0v, n1v)                                                                   \
  {                                                                                      \
    int n0 = (n0v), n1 = (n1v);                                                          \
    for (;;) {                                                                           \
      int a_ = __hip_atomic_load(pf0a, __ATOMIC_RELAXED, __HIP_MEMORY_SCOPE_AGENT);      \
      int b_ = __hip_atomic_load(pf0b, __ATOMIC_RELAXED, __HIP_MEMORY_SCOPE_AGENT);      \
      int c_ = __hip_atomic_load(pf1a, __ATOMIC_RELAXED, __HIP_MEMORY_SCOPE_AGENT);      \
      int d_ = __hip_atomic_load(pf1b, __ATOMIC_RELAXED, __HIP_MEMORY_SCOPE_AGENT);      \
      if (__all((a_ >= n0) && (b_ >= n0) && (c_ >= n1) && (d_ >= n1))) break;            \
      __builtin_amdgcn_s_sleep(1);                                                       \
    }                                                                                    \
  }

#define CRED_AND_POINTWISE(HOUT, HALL)                                                   \
  {                                                                                      \
    _Pragma("unroll") for (int rf = 0; rf < 4; ++rf)                                     \
      _Pragma("unroll") for (int cf = 0; cf < 2; ++cf)                                   \
        _Pragma("unroll") for (int r = 0; r < 4; ++r)                                    \
          cred[w][rf * 16 + (lane >> 4) * 4 + r][cf * 16 + l15] = acc[rf][cf][r];        \
    __syncthreads();                                                                     \
    float ip = bI, fp = bF, gp = bG, op = bO;                                            \
    _Pragma("unroll") for (int ww = 0; ww < 8; ++ww) {                                   \
      ip += cred[ww][m][jl];                                                             \
      fp += cred[ww][m][8 + jl];                                                         \
      gp += cred[ww][m][16 + jl];                                                        \
      op += cred[ww][m][24 + jl];                                                       \
    }                                                                                    \
    float ig = 1.f / (1.f + __expf(-ip));                                                \
    float fg = 1.f / (1.f + __expf(-fp));                                                \
    float ea = __expf(-2.f * fabsf(gp));                                                 \
    float gg = copysignf((1.f - ea) / (1.f + ea), gp);                                   \
    float og = 1.f / (1.f + __expf(-op));                                                \
    creg = fg * creg + ig * gg;                                                          \
    float eb = __expf(-2.f * fabsf(creg));                                               \
    float hval = og * copysignf((1.f - eb) / (1.f + eb), creg);                          \
    size_t idx = (size_t)m * 1024 + jg;                                                  \
    union { f16 h; unsigned short s; } cv; cv.h = (f16)hval;                             \
    __hip_atomic_store((unsigned short*)((HOUT) + idx), cv.s,                            \
                       __ATOMIC_RELAXED, __HIP_MEMORY_SCOPE_AGENT);                      \
    if (HALL) ((f16*)(HALL))[idx] = cv.h;                                                \
    __syncthreads(); /* drains vmcnt(0): h stores ack'd at LLC */                        \
    if (tid == 0)                                                                        \
      __hip_atomic_store(myflag, t + 1, __ATOMIC_RELAXED, __HIP_MEMORY_SCOPE_AGENT);     \
  }

  if (layer == 0) {
    const int KK = 6;  // kPer = 192, Ktot = 1536
    f16x8 wreg[6][2];
#pragma unroll
    for (int kk = 0; kk < KK; ++kk)
#pragma unroll
      for (int cf = 0; cf < 2; ++cf)
        wreg[kk][cf] = *(const f16x8*)(W0f + ((size_t)((jb * 8 + w) * KK + kk) * 2 + cf) * 512 + lane * 8);
#pragma unroll
    for (int kk = 0; kk < KK; ++kk)
      asm volatile("" : "+v"(wreg[kk][0]), "+v"(wreg[kk][1]));

    const int kbeg = w * 192;
    for (int t = 0; t < 512; ++t) {
      const f16* A0 = x16 + (size_t)t * 32768;
      const f16* A1 = h0buf + (size_t)((t + 3) & 3) * 65536;  // h0_{t-1}
      f16* hout = h0buf + (size_t)(t & 3) * 65536;            // h0_t

      POLL(t, t - 3);

      f16x8 af[4][4];
      auto loadA = [&](int kk, int slot) {
        int k = kbeg + kk * 32 + q8;
        if (k < 512) {
          const f16* ap = A0 + k;
#pragma unroll
          for (int rf = 0; rf < 4; ++rf)
            af[slot][rf] = *(const f16x8*)(ap + (size_t)(rf * 16 + l15) * 512);
        } else {
          const f16* ap = A1 + (k - 512);
#pragma unroll
          for (int rf = 0; rf < 4; ++rf) {
            const unsigned long long* p =
                (const unsigned long long*)(ap + (size_t)(rf * 16 + l15) * 1024);
            U16 u;
            u.u[0] = __hip_atomic_load(p, __ATOMIC_RELAXED, __HIP_MEMORY_SCOPE_AGENT);
            u.u[1] = __hip_atomic_load(p + 1, __ATOMIC_RELAXED, __HIP_MEMORY_SCOPE_AGENT);
            af[slot][rf] = u.v;
          }
        }
      };

      loadA(0, 0); loadA(1, 1); loadA(2, 2); loadA(3, 3);

      f32x4 acc[4][2];
#pragma unroll
      for (int i = 0; i < 4; ++i) {
        acc[i][0] = f32x4{0.f, 0.f, 0.f, 0.f};
        acc[i][1] = f32x4{0.f, 0.f, 0.f, 0.f};
      }

#pragma unroll
      for (int kk = 0; kk < 6; ++kk) {
#pragma unroll
        for (int rf = 0; rf < 4; ++rf) {
          acc[rf][0] = MFMA16(af[kk & 3][rf], wreg[kk][0], acc[rf][0]);
          acc[rf][1] = MFMA16(af[kk & 3][rf], wreg[kk][1], acc[rf][1]);
        }
        if (kk + 4 < 6) loadA(kk + 4, kk & 3);
      }

      CRED_AND_POINTWISE(hout, (f16*)nullptr);
    }
  } else {
    const int KK = 8;  // kPer = 256, Ktot = 2048
    f16x8 wreg[8][2];
#pragma unroll
    for (int kk = 0; kk < KK; ++kk)
#pragma unroll
      for (int cf = 0; cf < 2; ++cf)
        wreg[kk][cf] = *(const f16x8*)(W1f + ((size_t)((jb * 8 + w) * KK + kk) * 2 + cf) * 512 + lane * 8);
#pragma unroll
    for (int kk = 0; kk < KK; ++kk)
      asm volatile("" : "+v"(wreg[kk][0]), "+v"(wreg[kk][1]));

    const int kbeg = w * 256;
    for (int t = 0; t < 512; ++t) {
      const f16* A0 = h0buf + (size_t)(t & 3) * 65536;        // h0_t
      const f16* A1 = h1buf + (size_t)((t + 3) & 3) * 65536;  // h1_{t-1}
      f16* hout = h1buf + (size_t)(t & 3) * 65536;            // h1_t
      f16* hall = h1all + (size_t)t * 65536;

      POLL(t + 1, t);

      f16x8 af[4][4];
      auto loadA = [&](int kk, int slot) {
        int k = kbeg + kk * 32 + q8;
        const f16* ap = (k < 1024) ? (A0 + k) : (A1 + (k - 1024));
#pragma unroll
        for (int rf = 0; rf < 4; ++rf) {
          const unsigned long long* p =
              (const unsigned long long*)(ap + (size_t)(rf * 16 + l15) * 1024);
          U16 u;
          u.u[0] = __hip_atomic_load(p, __ATOMIC_RELAXED, __HIP_MEMORY_SCOPE_AGENT);
          u.u[1] = __hip_atomic_load(p + 1, __ATOMIC_RELAXED, __HIP_MEMORY_SCOPE_AGENT);
          af[slot][rf] = u.v;
        }
      };

      loadA(0, 0); loadA(1, 1); loadA(2, 2); loadA(3, 3);

      f32x4 acc[4][2];
#pragma unroll
      for (int i = 0; i < 4; ++i) {
        acc[i][0] = f32x4{0.f, 0.f, 0.f, 0.f};
        acc[i][1] = f32x4{0.f, 0.f, 0.f, 0.f};
      }

#pragma unroll
      for (int kk = 0; kk < 8; ++kk) {
#pragma unroll
        for (int rf = 0; rf < 4; ++rf) {
          acc[rf][0] = MFMA16(af[kk & 3][rf], wreg[kk][0], acc[rf][0]);
          acc[rf][1] = MFMA16(af[kk & 3][rf], wreg[kk][1], acc[rf][1]);
        }
        if (kk + 4 < 8) loadA(kk + 4, kk & 3);
      }

      CRED_AND_POINTWISE(hout, hall);
    }
  }
#undef POLL
#undef CRED_AND_POINTWISE
}

// ---------------- final FC ----------------
__global__ __launch_bounds__(512, 1)
void k_fc(const f16* __restrict__ h1all, const f16* __restrict__ Wfc16,
          const float* __restrict__ bfc, float* __restrict__ out) {
  const int s = blockIdx.x;
  const f16* A = h1all + (size_t)s * 65536;
  __shared__ float credf[8][64][68];

  const int w = threadIdx.x >> 6;
  const int lane = threadIdx.x & 63;
  const int l15 = lane & 15;
  const int ksub = (lane >> 4) << 3;

  f32x4 acc[4][4];
#pragma unroll
  for (int i = 0; i < 4; ++i)
#pragma unroll
    for (int j = 0; j < 4; ++j) acc[i][j] = f32x4{0.f, 0.f, 0.f, 0.f};

  const int kbeg = w * 128, kend = kbeg + 128;
  f16x8 af0[4], bf0[4], af1[4], bf1[4];

  auto LOADK = [&](int kc, f16x8(&a)[4], f16x8(&b)[4]) {
    const f16* ap = A + kc + ksub;
#pragma unroll
    for (int rf = 0; rf < 4; ++rf)
      a[rf] = *(const f16x8*)(ap + (size_t)(rf * 16 + l15) * 1024);
    const f16* bp = Wfc16 + kc + ksub;
#pragma unroll
    for (int cf = 0; cf < 4; ++cf)
      b[cf] = *(const f16x8*)(bp + (size_t)(cf * 16 + l15) * 1024);
  };

  LOADK(kbeg, af0, bf0);
  for (int kc = kbeg; kc < kend; kc += 64) {
    LOADK(kc + 32, af1, bf1);
#pragma unroll
    for (int rf = 0; rf < 4; ++rf)
#pragma unroll
      for (int cf = 0; cf < 4; ++cf) acc[rf][cf] = MFMA16(af0[rf], bf0[cf], acc[rf][cf]);
    if (kc + 64 < kend) LOADK(kc + 64, af0, bf0);
#pragma unroll
    for (int rf = 0; rf < 4; ++rf)
#pragma unroll
      for (int cf = 0; cf < 4; ++cf) acc[rf][cf] = MFMA16(af1[rf], bf1[cf], acc[rf][cf]);
  }

#pragma unroll
  for (int rf = 0; rf < 4; ++rf)
#pragma unroll
    for (int cf = 0; cf < 4; ++cf)
#pragma unroll
      for (int r = 0; r < 4; ++r)
        credf[w][rf * 16 + (lane >> 4) * 4 + r][cf * 16 + l15] = acc[rf][cf][r];

  __syncthreads();

  int m = threadIdx.x >> 3;
  int cbase = (threadIdx.x & 7) * 8;
#pragma unroll
  for (int u = 0; u < 8; ++u) {
    int col = cbase + u;
    float v = bfc[col];
#pragma unroll
    for (int ww = 0; ww < 8; ++ww) v += credf[ww][m][col];
    out[((size_t)m * 512 + s) * 64 + col] = v;
  }
}

// ---------------- host ----------------
extern "C" void kernel_launch(void* const* d_in, const int* in_sizes, int n_in,
                              void* d_out, int out_size, void* d_ws, size_t ws_size,
                              hipStream_t stream) {
  const float* x    = (const float*)d_in[0];
  const float* Wih0 = (const float*)d_in[1];
  const float* Whh0 = (const float*)d_in[2];
  const float* bih0 = (const float*)d_in[3];
  const float* bhh0 = (const float*)d_in[4];
  const float* Wih1 = (const float*)d_in[5];
  const float* Whh1 = (const float*)d_in[6];
  const float* bih1 = (const float*)d_in[7];
  const float* bhh1 = (const float*)d_in[8];
  const float* Wfc  = (const float*)d_in[9];
  const float* bfc  = (const float*)d_in[10];
  float* out = (float*)d_out;

  char* ws = (char*)d_ws;
  f16*   W0f   = (f16*)(ws + 0);           // 12288 frags * 1KB = 12,582,912
  f16*   W1f   = (f16*)(ws + 12582912);    // 16384 frags * 1KB = 16,777,216
  f16*   Wfc16 = (f16*)(ws + 29360128);    // 131,072
  float* b0r   = (float*)(ws + 29491200);  // 16,384
  float* b1r   = (float*)(ws + 29507584);  // 16,384
  f16*   x16   = (f16*)(ws + 29523968);    // 33,554,432
  f16*   h1all = (f16*)(ws + 63078400);    // 67,108,864
  f16*   h0buf = (f16*)(ws + 130187264);   // 4 * 131,072 = 524,288
  f16*   h1buf = (f16*)(ws + 130711552);   // 524,288
  int*   flags = (int*)(ws + 131235840);   // 32,768  (end 131,268,608)

  k_conv_x<<<8192, 256, 0, stream>>>(x, x16);
  k_conv_wfrag<<<12288, 64, 0, stream>>>(Wih0, Whh0, W0f, 512, 6, 192);
  k_conv_wfrag<<<16384, 64, 0, stream>>>(Wih1, Whh1, W1f, 1024, 8, 256);
  k_conv_bias<<<64, 64, 0, stream>>>(bih0, bhh0, b0r);
  k_conv_bias<<<64, 64, 0, stream>>>(bih1, bhh1, b1r);
  k_conv_wfc<<<256, 256, 0, stream>>>(Wfc, Wfc16);
  // zero h ring buffers + flags every launch (determinism under graph replay)
  hipMemsetAsync(ws + 130187264, 0, 524288 * 2 + 32768, stream);

  {
    const f16* x16c = x16; const f16* W0fc = W0f; const float* b0rc = b0r;
    const f16* W1fc = W1f; const float* b1rc = b1r;
    f16 *p0 = h0buf, *p1 = h1buf, *ph = h1all;
    int* fl = flags;
    void* kargs[] = { &x16c, &W0fc, &b0rc, &W1fc, &b1rc, &p0, &p1, &ph, &fl };
    hipLaunchCooperativeKernel((void*)k_persist, dim3(256), dim3(512), kargs, 0, stream);
  }

  k_fc<<<512, 512, 0, stream>>>(h1all, Wfc16, bfc, out);
}

// Round 6
// 9036.479 us; speedup vs baseline: 5.2368x; 1.0237x over previous
//
#include <hip/hip_runtime.h>
#include <stdint.h>

typedef _Float16 f16;
typedef _Float16 f16x8 __attribute__((ext_vector_type(8)));
typedef float f32x4 __attribute__((ext_vector_type(4)));

#define MFMA16(a, b, c) __builtin_amdgcn_mfma_f32_16x16x32_f16((a), (b), (c), 0, 0, 0)

// Sizes: B=64, S=512, I=512, H=1024, 4H=4096, O=64

// ---------------- prep kernels ----------------

// x (B,S,I) f32 -> x16 (S,B,I) f16; flat, 8 elems/thread
__global__ void k_conv_x(const float* __restrict__ x, f16* __restrict__ x16) {
  int i = blockIdx.x * 256 + threadIdx.x;   // 2,097,152 threads
  int o = i * 8;
  int s = o >> 15, b = (o >> 9) & 63, c = o & 511;
  const float* src = x + (size_t)b * 262144 + (size_t)s * 512 + c;
  float4 v0 = *(const float4*)(src);
  float4 v1 = *(const float4*)(src + 4);
  union { f16 h[8]; f16x8 v; } t;
  t.h[0] = (f16)v0.x; t.h[1] = (f16)v0.y; t.h[2] = (f16)v0.z; t.h[3] = (f16)v0.w;
  t.h[4] = (f16)v1.x; t.h[5] = (f16)v1.y; t.h[6] = (f16)v1.z; t.h[7] = (f16)v1.w;
  *(f16x8*)(x16 + o) = t.v;
}

// Weights -> per-(slab,wave,kk,colhalf) MFMA B-fragments, f32->f16.
// fid = ((jb*8 + w)*KK + kk)*2 + cf. Lane holds W[c][k..k+7]:
//   slab col c = cf*16 + (lane&15)  -> gate row g = (c>>3)*1024 + jb*8 + (c&7)
//   k = w*kPer + kk*32 + (lane>>4)*8
__global__ void k_conv_wfrag(const float* __restrict__ Wih, const float* __restrict__ Whh,
                             f16* __restrict__ Wf, int KI, int KK, int kPer) {
  int fid = blockIdx.x;
  int lane = threadIdx.x;
  int cf = fid & 1; int rest = fid >> 1;
  int kk = rest % KK; rest /= KK; int w = rest & 7; int jb = rest >> 3;
  int c = cf * 16 + (lane & 15);
  int g = (c >> 3) * 1024 + jb * 8 + (c & 7);
  int k = w * kPer + kk * 32 + ((lane >> 4) << 3);
  const float* src = (k < KI) ? (Wih + (size_t)g * KI + k)
                              : (Whh + (size_t)g * 1024 + (k - KI));
  union { f16 h[8]; f16x8 v; } t;
#pragma unroll
  for (int i = 0; i < 8; ++i) t.h[i] = (f16)src[i];
  *(f16x8*)(Wf + ((size_t)fid * 64 + lane) * 8) = t.v;
}

__global__ void k_conv_bias(const float* __restrict__ bih, const float* __restrict__ bhh,
                            float* __restrict__ br) {
  int d = blockIdx.x * 64 + threadIdx.x;  // 4096
  int jb = d >> 5, r = d & 31;
  int g = (r >> 3) * 1024 + jb * 8 + (r & 7);
  br[d] = bih[g] + bhh[g];
}

__global__ void k_conv_wfc(const float* __restrict__ Wfc, f16* __restrict__ Wfc16) {
  int i = blockIdx.x * 256 + threadIdx.x;
  Wfc16[i] = (f16)Wfc[i];
}

// ---------------- persistent pipelined LSTM ----------------
// 256 blocks x 512 threads, cooperative. Blocks 0..127: layer0 slab jb,
// 128..255: layer1 slab jb. Weights in VGPRs; h via relaxed agent-scope
// bypass atomics (no fences, L2 never invalidated). Sync: per-block flags
// on private 128B lines; blocks jb<8 of each layer aggregate their group's
// 16 flags into one of 16 group-flags packed in ONE 64B line; consumers
// (wave 0 only) poll that single line -> 1 coalesced fabric transaction
// per poll iteration instead of a 256-line storm from all 8 waves.
__global__ __launch_bounds__(512, 2)
void k_persist(const f16* __restrict__ x16,
               const f16* __restrict__ W0f, const float* __restrict__ b0r,
               const f16* __restrict__ W1f, const float* __restrict__ b1r,
               f16* __restrict__ h0buf, f16* __restrict__ h1buf,
               f16* __restrict__ h1all, int* flags, int* gflags) {
  const int layer = blockIdx.x >> 7;
  const int jb = blockIdx.x & 127;

  __shared__ float cred[8][64][36];  // stride 36: write 2-way, gate-read 2-way

  int* flag0 = flags;          // 128 flags, 128B apart
  int* flag1 = flags + 4096;
  int* myflag = (layer ? flag1 : flag0) + jb * 32;

  const int tid = threadIdx.x;
  const int w = tid >> 6, lane = tid & 63;
  const int l15 = lane & 15, q8 = (lane >> 4) << 3;
  const int m = tid >> 3, jl = tid & 7, jg = jb * 8 + jl;

  const float* bias = (layer ? b1r : b0r) + jb * 32;
  const float bI = bias[jl], bF = bias[8 + jl], bG = bias[16 + jl], bO = bias[24 + jl];
  float creg = 0.f;

  // group-flag poll: lane reads gflags[lane&15]; lanes 0-7 check layer0 need,
  // lanes 8-15 check layer1 need (duplicated across the 4 16-lane groups).
  const int* gp = gflags + l15;
  const bool isg1 = l15 >= 8;
  // aggregator poll pointer (blocks jb<8 only): flag line of group member
  const int* aggp = (layer ? flag1 : flag0) + (jb * 16 + l15) * 32;
  int* myg = gflags + (layer ? 8 : 0) + jb;

  union U16 { unsigned long long u[2]; f16x8 v; };

#define POLLG(n0v, n1v)                                                                  \
  {                                                                                      \
    int need_ = isg1 ? (n1v) : (n0v);                                                    \
    if (w == 0) {                                                                        \
      for (;;) {                                                                         \
        int v_ = __hip_atomic_load(gp, __ATOMIC_RELAXED, __HIP_MEMORY_SCOPE_AGENT);      \
        if (__all(v_ >= need_)) break;                                                   \
        __builtin_amdgcn_s_sleep(2);                                                     \
      }                                                                                  \
    }                                                                                    \
    __syncthreads();                                                                     \
  }

#define CRED_AND_POINTWISE(HOUT, HALL)                                                   \
  {                                                                                      \
    _Pragma("unroll") for (int rf = 0; rf < 4; ++rf)                                     \
      _Pragma("unroll") for (int cf = 0; cf < 2; ++cf)                                   \
        _Pragma("unroll") for (int r = 0; r < 4; ++r)                                    \
          cred[w][rf * 16 + (lane >> 4) * 4 + r][cf * 16 + l15] = acc[rf][cf][r];        \
    __syncthreads();                                                                     \
    float ip = bI, fp = bF, gp2 = bG, op = bO;                                           \
    _Pragma("unroll") for (int ww = 0; ww < 8; ++ww) {                                   \
      ip += cred[ww][m][jl];                                                             \
      fp += cred[ww][m][8 + jl];                                                         \
      gp2 += cred[ww][m][16 + jl];                                                       \
      op += cred[ww][m][24 + jl];                                                        \
    }                                                                                    \
    float ig = 1.f / (1.f + __expf(-ip));                                                \
    float fg = 1.f / (1.f + __expf(-fp));                                                \
    float ea = __expf(-2.f * fabsf(gp2));                                                \
    float gg = copysignf((1.f - ea) / (1.f + ea), gp2);                                  \
    float og = 1.f / (1.f + __expf(-op));                                                \
    creg = fg * creg + ig * gg;                                                          \
    float eb = __expf(-2.f * fabsf(creg));                                               \
    float hval = og * copysignf((1.f - eb) / (1.f + eb), creg);                          \
    size_t idx = (size_t)m * 1024 + jg;                                                  \
    union { f16 h; unsigned short s; } cv; cv.h = (f16)hval;                             \
    __hip_atomic_store((unsigned short*)((HOUT) + idx), cv.s,                            \
                       __ATOMIC_RELAXED, __HIP_MEMORY_SCOPE_AGENT);                      \
    if (HALL) ((f16*)(HALL))[idx] = cv.h;                                                \
    __syncthreads(); /* drains vmcnt(0): h stores ack'd at LLC */                        \
    if (tid == 0)                                                                        \
      __hip_atomic_store(myflag, t + 1, __ATOMIC_RELAXED, __HIP_MEMORY_SCOPE_AGENT);     \
    if (jb < 8 && w == 0) {                                                              \
      for (;;) {                                                                         \
        int v_ = __hip_atomic_load(aggp, __ATOMIC_RELAXED, __HIP_MEMORY_SCOPE_AGENT);    \
        if (__all(v_ >= t + 1)) break;                                                   \
        __builtin_amdgcn_s_sleep(1);                                                     \
      }                                                                                  \
      if (lane == 0)                                                                     \
        __hip_atomic_store(myg, t + 1, __ATOMIC_RELAXED, __HIP_MEMORY_SCOPE_AGENT);      \
    }                                                                                    \
  }

  if (layer == 0) {
    const int KK = 6;  // kPer = 192, Ktot = 1536
    f16x8 wreg[6][2];
#pragma unroll
    for (int kk = 0; kk < KK; ++kk)
#pragma unroll
      for (int cf = 0; cf < 2; ++cf)
        wreg[kk][cf] = *(const f16x8*)(W0f + ((size_t)((jb * 8 + w) * KK + kk) * 2 + cf) * 512 + lane * 8);
#pragma unroll
    for (int kk = 0; kk < KK; ++kk)
      asm volatile("" : "+v"(wreg[kk][0]), "+v"(wreg[kk][1]));

    const int kbeg = w * 192;
    for (int t = 0; t < 512; ++t) {
      const f16* A0 = x16 + (size_t)t * 32768;
      const f16* A1 = h0buf + (size_t)((t + 3) & 3) * 65536;  // h0_{t-1}
      f16* hout = h0buf + (size_t)(t & 3) * 65536;            // h0_t

      POLLG(t, t - 3);

      f16x8 af[4][4];
      auto loadA = [&](int kk, int slot) {
        int k = kbeg + kk * 32 + q8;
        if (k < 512) {
          const f16* ap = A0 + k;
#pragma unroll
          for (int rf = 0; rf < 4; ++rf)
            af[slot][rf] = *(const f16x8*)(ap + (size_t)(rf * 16 + l15) * 512);
        } else {
          const f16* ap = A1 + (k - 512);
#pragma unroll
          for (int rf = 0; rf < 4; ++rf) {
            const unsigned long long* p =
                (const unsigned long long*)(ap + (size_t)(rf * 16 + l15) * 1024);
            U16 u;
            u.u[0] = __hip_atomic_load(p, __ATOMIC_RELAXED, __HIP_MEMORY_SCOPE_AGENT);
            u.u[1] = __hip_atomic_load(p + 1, __ATOMIC_RELAXED, __HIP_MEMORY_SCOPE_AGENT);
            af[slot][rf] = u.v;
          }
        }
      };

      loadA(0, 0); loadA(1, 1); loadA(2, 2); loadA(3, 3);

      f32x4 acc[4][2];
#pragma unroll
      for (int i = 0; i < 4; ++i) {
        acc[i][0] = f32x4{0.f, 0.f, 0.f, 0.f};
        acc[i][1] = f32x4{0.f, 0.f, 0.f, 0.f};
      }

#pragma unroll
      for (int kk = 0; kk < 6; ++kk) {
#pragma unroll
        for (int rf = 0; rf < 4; ++rf) {
          acc[rf][0] = MFMA16(af[kk & 3][rf], wreg[kk][0], acc[rf][0]);
          acc[rf][1] = MFMA16(af[kk & 3][rf], wreg[kk][1], acc[rf][1]);
        }
        if (kk + 4 < 6) loadA(kk + 4, kk & 3);
      }

      CRED_AND_POINTWISE(hout, (f16*)nullptr);
    }
  } else {
    const int KK = 8;  // kPer = 256, Ktot = 2048
    f16x8 wreg[8][2];
#pragma unroll
    for (int kk = 0; kk < KK; ++kk)
#pragma unroll
      for (int cf = 0; cf < 2; ++cf)
        wreg[kk][cf] = *(const f16x8*)(W1f + ((size_t)((jb * 8 + w) * KK + kk) * 2 + cf) * 512 + lane * 8);
#pragma unroll
    for (int kk = 0; kk < KK; ++kk)
      asm volatile("" : "+v"(wreg[kk][0]), "+v"(wreg[kk][1]));

    const int kbeg = w * 256;
    for (int t = 0; t < 512; ++t) {
      const f16* A0 = h0buf + (size_t)(t & 3) * 65536;        // h0_t
      const f16* A1 = h1buf + (size_t)((t + 3) & 3) * 65536;  // h1_{t-1}
      f16* hout = h1buf + (size_t)(t & 3) * 65536;            // h1_t
      f16* hall = h1all + (size_t)t * 65536;

      POLLG(t + 1, t);

      f16x8 af[4][4];
      auto loadA = [&](int kk, int slot) {
        int k = kbeg + kk * 32 + q8;
        const f16* ap = (k < 1024) ? (A0 + k) : (A1 + (k - 1024));
#pragma unroll
        for (int rf = 0; rf < 4; ++rf) {
          const unsigned long long* p =
              (const unsigned long long*)(ap + (size_t)(rf * 16 + l15) * 1024);
          U16 u;
          u.u[0] = __hip_atomic_load(p, __ATOMIC_RELAXED, __HIP_MEMORY_SCOPE_AGENT);
          u.u[1] = __hip_atomic_load(p + 1, __ATOMIC_RELAXED, __HIP_MEMORY_SCOPE_AGENT);
          af[slot][rf] = u.v;
        }
      };

      loadA(0, 0); loadA(1, 1); loadA(2, 2); loadA(3, 3);

      f32x4 acc[4][2];
#pragma unroll
      for (int i = 0; i < 4; ++i) {
        acc[i][0] = f32x4{0.f, 0.f, 0.f, 0.f};
        acc[i][1] = f32x4{0.f, 0.f, 0.f, 0.f};
      }

#pragma unroll
      for (int kk = 0; kk < 8; ++kk) {
#pragma unroll
        for (int rf = 0; rf < 4; ++rf) {
          acc[rf][0] = MFMA16(af[kk & 3][rf], wreg[kk][0], acc[rf][0]);
          acc[rf][1] = MFMA16(af[kk & 3][rf], wreg[kk][1], acc[rf][1]);
        }
        if (kk + 4 < 8) loadA(kk + 4, kk & 3);
      }

      CRED_AND_POINTWISE(hout, hall);
    }
  }
#undef POLLG
#undef CRED_AND_POINTWISE
}

// ---------------- final FC ----------------
__global__ __launch_bounds__(512, 1)
void k_fc(const f16* __restrict__ h1all, const f16* __restrict__ Wfc16,
          const float* __restrict__ bfc, float* __restrict__ out) {
  const int s = blockIdx.x;
  const f16* A = h1all + (size_t)s * 65536;
  __shared__ float credf[8][64][68];

  const int w = threadIdx.x >> 6;
  const int lane = threadIdx.x & 63;
  const int l15 = lane & 15;
  const int ksub = (lane >> 4) << 3;

  f32x4 acc[4][4];
#pragma unroll
  for (int i = 0; i < 4; ++i)
#pragma unroll
    for (int j = 0; j < 4; ++j) acc[i][j] = f32x4{0.f, 0.f, 0.f, 0.f};

  const int kbeg = w * 128, kend = kbeg + 128;
  f16x8 af0[4], bf0[4], af1[4], bf1[4];

  auto LOADK = [&](int kc, f16x8(&a)[4], f16x8(&b)[4]) {
    const f16* ap = A + kc + ksub;
#pragma unroll
    for (int rf = 0; rf < 4; ++rf)
      a[rf] = *(const f16x8*)(ap + (size_t)(rf * 16 + l15) * 1024);
    const f16* bp = Wfc16 + kc + ksub;
#pragma unroll
    for (int cf = 0; cf < 4; ++cf)
      b[cf] = *(const f16x8*)(bp + (size_t)(cf * 16 + l15) * 1024);
  };

  LOADK(kbeg, af0, bf0);
  for (int kc = kbeg; kc < kend; kc += 64) {
    LOADK(kc + 32, af1, bf1);
#pragma unroll
    for (int rf = 0; rf < 4; ++rf)
#pragma unroll
      for (int cf = 0; cf < 4; ++cf) acc[rf][cf] = MFMA16(af0[rf], bf0[cf], acc[rf][cf]);
    if (kc + 64 < kend) LOADK(kc + 64, af0, bf0);
#pragma unroll
    for (int rf = 0; rf < 4; ++rf)
#pragma unroll
      for (int cf = 0; cf < 4; ++cf) acc[rf][cf] = MFMA16(af1[rf], bf1[cf], acc[rf][cf]);
  }

#pragma unroll
  for (int rf = 0; rf < 4; ++rf)
#pragma unroll
    for (int cf = 0; cf < 4; ++cf)
#pragma unroll
      for (int r = 0; r < 4; ++r)
        credf[w][rf * 16 + (lane >> 4) * 4 + r][cf * 16 + l15] = acc[rf][cf][r];

  __syncthreads();

  int m = threadIdx.x >> 3;
  int cbase = (threadIdx.x & 7) * 8;
#pragma unroll
  for (int u = 0; u < 8; ++u) {
    int col = cbase + u;
    float v = bfc[col];
#pragma unroll
    for (int ww = 0; ww < 8; ++ww) v += credf[ww][m][col];
    out[((size_t)m * 512 + s) * 64 + col] = v;
  }
}

// ---------------- host ----------------
extern "C" void kernel_launch(void* const* d_in, const int* in_sizes, int n_in,
                              void* d_out, int out_size, void* d_ws, size_t ws_size,
                              hipStream_t stream) {
  const float* x    = (const float*)d_in[0];
  const float* Wih0 = (const float*)d_in[1];
  const float* Whh0 = (const float*)d_in[2];
  const float* bih0 = (const float*)d_in[3];
  const float* bhh0 = (const float*)d_in[4];
  const float* Wih1 = (const float*)d_in[5];
  const float* Whh1 = (const float*)d_in[6];
  const float* bih1 = (const float*)d_in[7];
  const float* bhh1 = (const float*)d_in[8];
  const float* Wfc  = (const float*)d_in[9];
  const float* bfc  = (const float*)d_in[10];
  float* out = (float*)d_out;

  char* ws = (char*)d_ws;
  f16*   W0f   = (f16*)(ws + 0);           // 12288 frags * 1KB = 12,582,912
  f16*   W1f   = (f16*)(ws + 12582912);    // 16384 frags * 1KB = 16,777,216
  f16*   Wfc16 = (f16*)(ws + 29360128);    // 131,072
  float* b0r   = (float*)(ws + 29491200);  // 16,384
  float* b1r   = (float*)(ws + 29507584);  // 16,384
  f16*   x16   = (f16*)(ws + 29523968);    // 33,554,432
  f16*   h1all = (f16*)(ws + 63078400);    // 67,108,864
  f16*   h0buf = (f16*)(ws + 130187264);   // 4 * 131,072 = 524,288
  f16*   h1buf = (f16*)(ws + 130711552);   // 524,288
  int*   flags = (int*)(ws + 131235840);   // 32,768
  int*   gfl   = (int*)(ws + 131268608);   // 64 B (one cache line, 16 ints)

  k_conv_x<<<8192, 256, 0, stream>>>(x, x16);
  k_conv_wfrag<<<12288, 64, 0, stream>>>(Wih0, Whh0, W0f, 512, 6, 192);
  k_conv_wfrag<<<16384, 64, 0, stream>>>(Wih1, Whh1, W1f, 1024, 8, 256);
  k_conv_bias<<<64, 64, 0, stream>>>(bih0, bhh0, b0r);
  k_conv_bias<<<64, 64, 0, stream>>>(bih1, bhh1, b1r);
  k_conv_wfc<<<256, 256, 0, stream>>>(Wfc, Wfc16);
  // zero h ring buffers + flags + gflags every launch (graph-replay determinism)
  hipMemsetAsync(ws + 130187264, 0, 524288 * 2 + 32768 + 64, stream);

  {
    const f16* x16c = x16; const f16* W0fc = W0f; const float* b0rc = b0r;
    const f16* W1fc = W1f; const float* b1rc = b1r;
    f16 *p0 = h0buf, *p1 = h1buf, *ph = h1all;
    int* fl = flags; int* gf = gfl;
    void* kargs[] = { &x16c, &W0fc, &b0rc, &W1fc, &b1rc, &p0, &p1, &ph, &fl, &gf };
    hipLaunchCooperativeKernel((void*)k_persist, dim3(256), dim3(512), kargs, 0, stream);
  }

  k_fc<<<512, 512, 0, stream>>>(h1all, Wfc16, bfc, out);
}

// Round 7
// 5467.141 us; speedup vs baseline: 8.6558x; 1.6529x over previous
//
#include <hip/hip_runtime.h>
#include <stdint.h>

typedef _Float16 f16;
typedef _Float16 f16x8 __attribute__((ext_vector_type(8)));
typedef float f32x4 __attribute__((ext_vector_type(4)));

#define MFMA16(a, b, c) __builtin_amdgcn_mfma_f32_16x16x32_f16((a), (b), (c), 0, 0, 0)

// Sizes: B=64, S=512, I=512, H=1024, 4H=4096, O=64

// ---------------- prep kernels ----------------

// x (B,S,I) f32 -> x16 (S,B,I) f16; flat, 8 elems/thread
__global__ void k_conv_x(const float* __restrict__ x, f16* __restrict__ x16) {
  int i = blockIdx.x * 256 + threadIdx.x;   // 2,097,152 threads
  int o = i * 8;
  int s = o >> 15, b = (o >> 9) & 63, c = o & 511;
  const float* src = x + (size_t)b * 262144 + (size_t)s * 512 + c;
  float4 v0 = *(const float4*)(src);
  float4 v1 = *(const float4*)(src + 4);
  union { f16 h[8]; f16x8 v; } t;
  t.h[0] = (f16)v0.x; t.h[1] = (f16)v0.y; t.h[2] = (f16)v0.z; t.h[3] = (f16)v0.w;
  t.h[4] = (f16)v1.x; t.h[5] = (f16)v1.y; t.h[6] = (f16)v1.z; t.h[7] = (f16)v1.w;
  *(f16x8*)(x16 + o) = t.v;
}

// Weights -> per-(slab,wave,kk,colhalf) MFMA B-fragments, f32->f16.
// fid = ((jb*8 + w)*KK + kk)*2 + cf. Lane holds W[c][k..k+7]:
//   slab col c = cf*16 + (lane&15)  -> gate row g = (c>>3)*1024 + jb*8 + (c&7)
//   k = w*kPer + kk*32 + (lane>>4)*8
__global__ void k_conv_wfrag(const float* __restrict__ Wih, const float* __restrict__ Whh,
                             f16* __restrict__ Wf, int KI, int KK, int kPer) {
  int fid = blockIdx.x;
  int lane = threadIdx.x;
  int cf = fid & 1; int rest = fid >> 1;
  int kk = rest % KK; rest /= KK; int w = rest & 7; int jb = rest >> 3;
  int c = cf * 16 + (lane & 15);
  int g = (c >> 3) * 1024 + jb * 8 + (c & 7);
  int k = w * kPer + kk * 32 + ((lane >> 4) << 3);
  const float* src = (k < KI) ? (Wih + (size_t)g * KI + k)
                              : (Whh + (size_t)g * 1024 + (k - KI));
  union { f16 h[8]; f16x8 v; } t;
#pragma unroll
  for (int i = 0; i < 8; ++i) t.h[i] = (f16)src[i];
  *(f16x8*)(Wf + ((size_t)fid * 64 + lane) * 8) = t.v;
}

__global__ void k_conv_bias(const float* __restrict__ bih, const float* __restrict__ bhh,
                            float* __restrict__ br) {
  int d = blockIdx.x * 64 + threadIdx.x;  // 4096
  int jb = d >> 5, r = d & 31;
  int g = (r >> 3) * 1024 + jb * 8 + (r & 7);
  br[d] = bih[g] + bhh[g];
}

__global__ void k_conv_wfc(const float* __restrict__ Wfc, f16* __restrict__ Wfc16) {
  int i = blockIdx.x * 256 + threadIdx.x;
  Wfc16[i] = (f16)Wfc[i];
}

// ---------------- persistent pipelined LSTM ----------------
// 256 blocks x 512 threads, cooperative. Blocks 0..127: layer0 slab jb,
// 128..255: layer1 slab jb. Weights in VGPRs. h-operand reads: plain
// global_load_dwordx4 with sc0 sc1 (LLC-coherent like the old atomics, but
// TA-coalesced, 16B wide) in a manually counted vmcnt pipeline (4 kk-groups
// = 16 loads in flight; per-kk s_waitcnt vmcnt(12/8/4/0) + sched_barrier).
// x16 reads same path without sc bits (L2-cached). No fences anywhere.
__global__ __launch_bounds__(512, 2)
void k_persist(const f16* __restrict__ x16,
               const f16* __restrict__ W0f, const float* __restrict__ b0r,
               const f16* __restrict__ W1f, const float* __restrict__ b1r,
               f16* __restrict__ h0buf, f16* __restrict__ h1buf,
               f16* __restrict__ h1all, int* flags, int* gflags) {
  const int layer = blockIdx.x >> 7;
  const int jb = blockIdx.x & 127;

  __shared__ float cred[8][64][36];  // stride 36: write 2-way, gate-read 2-way

  int* flag0 = flags;          // 128 flags, 128B apart
  int* flag1 = flags + 4096;
  int* myflag = (layer ? flag1 : flag0) + jb * 32;

  const int tid = threadIdx.x;
  const int w = tid >> 6, lane = tid & 63;
  const int l15 = lane & 15, q8 = (lane >> 4) << 3;
  const int m = tid >> 3, jl = tid & 7, jg = jb * 8 + jl;

  const float* bias = (layer ? b1r : b0r) + jb * 32;
  const float bI = bias[jl], bF = bias[8 + jl], bG = bias[16 + jl], bO = bias[24 + jl];
  float creg = 0.f;

  // group-flag poll: lane reads gflags[lane&15]; lanes 0-7 carry layer0 need,
  // lanes 8-15 layer1 need.
  const int* gp = gflags + l15;
  const bool isg1 = l15 >= 8;
  const int* aggp = (layer ? flag1 : flag0) + (jb * 16 + l15) * 32;
  int* myg = gflags + (layer ? 8 : 0) + jb;

#define POLLG(n0v, n1v)                                                                  \
  {                                                                                      \
    int need_ = isg1 ? (n1v) : (n0v);                                                    \
    if (w == 0) {                                                                        \
      for (;;) {                                                                         \
        int v_ = __hip_atomic_load(gp, __ATOMIC_RELAXED, __HIP_MEMORY_SCOPE_AGENT);      \
        if (__all(v_ >= need_)) break;                                                   \
        __builtin_amdgcn_s_sleep(2);                                                     \
      }                                                                                  \
    }                                                                                    \
    __syncthreads();                                                                     \
  }

#define CRED_AND_POINTWISE(HOUT, HALL)                                                   \
  {                                                                                      \
    _Pragma("unroll") for (int rf = 0; rf < 4; ++rf)                                     \
      _Pragma("unroll") for (int cf = 0; cf < 2; ++cf)                                   \
        _Pragma("unroll") for (int r = 0; r < 4; ++r)                                    \
          cred[w][rf * 16 + (lane >> 4) * 4 + r][cf * 16 + l15] = acc[rf][cf][r];        \
    __syncthreads();                                                                     \
    float ip = bI, fp = bF, gp2 = bG, op = bO;                                           \
    _Pragma("unroll") for (int ww = 0; ww < 8; ++ww) {                                   \
      ip += cred[ww][m][jl];                                                             \
      fp += cred[ww][m][8 + jl];                                                         \
      gp2 += cred[ww][m][16 + jl];                                                       \
      op += cred[ww][m][24 + jl];                                                        \
    }                                                                                    \
    float ig = 1.f / (1.f + __expf(-ip));                                                \
    float fg = 1.f / (1.f + __expf(-fp));                                                \
    float ea = __expf(-2.f * fabsf(gp2));                                                \
    float gg = copysignf((1.f - ea) / (1.f + ea), gp2);                                  \
    float og = 1.f / (1.f + __expf(-op));                                                \
    creg = fg * creg + ig * gg;                                                          \
    float eb = __expf(-2.f * fabsf(creg));                                               \
    float hval = og * copysignf((1.f - eb) / (1.f + eb), creg);                          \
    size_t idx = (size_t)m * 1024 + jg;                                                  \
    union { f16 h; unsigned short s; } cv; cv.h = (f16)hval;                             \
    __hip_atomic_store((unsigned short*)((HOUT) + idx), cv.s,                            \
                       __ATOMIC_RELAXED, __HIP_MEMORY_SCOPE_AGENT);                      \
    if (HALL) ((f16*)(HALL))[idx] = cv.h;                                                \
    __syncthreads(); /* drains vmcnt(0): h stores ack'd at LLC */                        \
    if (tid == 0)                                                                        \
      __hip_atomic_store(myflag, t + 1, __ATOMIC_RELAXED, __HIP_MEMORY_SCOPE_AGENT);     \
    if (jb < 8 && w == 0) {                                                              \
      for (;;) {                                                                         \
        int v_ = __hip_atomic_load(aggp, __ATOMIC_RELAXED, __HIP_MEMORY_SCOPE_AGENT);    \
        if (__all(v_ >= t + 1)) break;                                                   \
        __builtin_amdgcn_s_sleep(1);                                                     \
      }                                                                                  \
      if (lane == 0)                                                                     \
        __hip_atomic_store(myg, t + 1, __ATOMIC_RELAXED, __HIP_MEMORY_SCOPE_AGENT);      \
    }                                                                                    \
  }

// coalesced LLC-coherent load (bypass L1+L2) / cached load, both vmcnt-counted
#define GLD_X(dst, addr)                                                                 \
  asm volatile("global_load_dwordx4 %0, %1, off sc0 sc1" : "=&v"(dst) : "v"(addr) : "memory")
#define GLD_C(dst, addr)                                                                 \
  asm volatile("global_load_dwordx4 %0, %1, off" : "=&v"(dst) : "v"(addr) : "memory")
#define WAITV(n)                                                                         \
  { asm volatile("s_waitcnt vmcnt(" #n ")" ::: "memory"); __builtin_amdgcn_sched_barrier(0); }

  if (layer == 0) {
    const int KK = 6;  // kPer = 192, Ktot = 1536
    f16x8 wreg[6][2];
#pragma unroll
    for (int kk = 0; kk < KK; ++kk)
#pragma unroll
      for (int cf = 0; cf < 2; ++cf)
        wreg[kk][cf] = *(const f16x8*)(W0f + ((size_t)((jb * 8 + w) * KK + kk) * 2 + cf) * 512 + lane * 8);
#pragma unroll
    for (int kk = 0; kk < KK; ++kk)
      asm volatile("" : "+v"(wreg[kk][0]), "+v"(wreg[kk][1]));

    const int kbeg = w * 192;
    for (int t = 0; t < 512; ++t) {
      const f16* A0 = x16 + (size_t)t * 32768;
      const f16* A1 = h0buf + (size_t)((t + 3) & 3) * 65536;  // h0_{t-1}
      f16* hout = h0buf + (size_t)(t & 3) * 65536;            // h0_t

      POLLG(t, t - 3);

      f16x8 af[4][4];
#define ISSUE0(kk)                                                                       \
      {                                                                                  \
        int k_ = kbeg + (kk) * 32 + q8;                                                  \
        if (k_ < 512) {                                                                  \
          const f16* ap_ = A0 + k_;                                                      \
          _Pragma("unroll") for (int rf = 0; rf < 4; ++rf)                               \
            GLD_C(af[(kk) & 3][rf], ap_ + (size_t)(rf * 16 + l15) * 512);                \
        } else {                                                                         \
          const f16* ap_ = A1 + (k_ - 512);                                              \
          _Pragma("unroll") for (int rf = 0; rf < 4; ++rf)                               \
            GLD_X(af[(kk) & 3][rf], ap_ + (size_t)(rf * 16 + l15) * 1024);               \
        }                                                                                \
      }
#define MF0(kk)                                                                          \
      { _Pragma("unroll") for (int rf = 0; rf < 4; ++rf) {                               \
          acc[rf][0] = MFMA16(af[(kk) & 3][rf], wreg[kk][0], acc[rf][0]);                \
          acc[rf][1] = MFMA16(af[(kk) & 3][rf], wreg[kk][1], acc[rf][1]); } }

      f32x4 acc[4][2];
#pragma unroll
      for (int i = 0; i < 4; ++i) {
        acc[i][0] = f32x4{0.f, 0.f, 0.f, 0.f};
        acc[i][1] = f32x4{0.f, 0.f, 0.f, 0.f};
      }

      ISSUE0(0) ISSUE0(1) ISSUE0(2) ISSUE0(3)
      WAITV(12) MF0(0) ISSUE0(4)
      WAITV(12) MF0(1) ISSUE0(5)
      WAITV(12) MF0(2)
      WAITV(8)  MF0(3)
      WAITV(4)  MF0(4)
      WAITV(0)  MF0(5)
#undef ISSUE0
#undef MF0

      CRED_AND_POINTWISE(hout, (f16*)nullptr);
    }
  } else {
    const int KK = 8;  // kPer = 256, Ktot = 2048
    f16x8 wreg[8][2];
#pragma unroll
    for (int kk = 0; kk < KK; ++kk)
#pragma unroll
      for (int cf = 0; cf < 2; ++cf)
        wreg[kk][cf] = *(const f16x8*)(W1f + ((size_t)((jb * 8 + w) * KK + kk) * 2 + cf) * 512 + lane * 8);
#pragma unroll
    for (int kk = 0; kk < KK; ++kk)
      asm volatile("" : "+v"(wreg[kk][0]), "+v"(wreg[kk][1]));

    const int kbeg = w * 256;
    for (int t = 0; t < 512; ++t) {
      const f16* A0 = h0buf + (size_t)(t & 3) * 65536;        // h0_t
      const f16* A1 = h1buf + (size_t)((t + 3) & 3) * 65536;  // h1_{t-1}
      f16* hout = h1buf + (size_t)(t & 3) * 65536;            // h1_t
      f16* hall = h1all + (size_t)t * 65536;

      POLLG(t + 1, t);

      f16x8 af[4][4];
#define ISSUE1(kk)                                                                       \
      {                                                                                  \
        int k_ = kbeg + (kk) * 32 + q8;                                                  \
        const f16* ap_ = (k_ < 1024) ? (A0 + k_) : (A1 + (k_ - 1024));                   \
        _Pragma("unroll") for (int rf = 0; rf < 4; ++rf)                                 \
          GLD_X(af[(kk) & 3][rf], ap_ + (size_t)(rf * 16 + l15) * 1024);                 \
      }
#define MF1(kk)                                                                          \
      { _Pragma("unroll") for (int rf = 0; rf < 4; ++rf) {                               \
          acc[rf][0] = MFMA16(af[(kk) & 3][rf], wreg[kk][0], acc[rf][0]);                \
          acc[rf][1] = MFMA16(af[(kk) & 3][rf], wreg[kk][1], acc[rf][1]); } }

      f32x4 acc[4][2];
#pragma unroll
      for (int i = 0; i < 4; ++i) {
        acc[i][0] = f32x4{0.f, 0.f, 0.f, 0.f};
        acc[i][1] = f32x4{0.f, 0.f, 0.f, 0.f};
      }

      ISSUE1(0) ISSUE1(1) ISSUE1(2) ISSUE1(3)
      WAITV(12) MF1(0) ISSUE1(4)
      WAITV(12) MF1(1) ISSUE1(5)
      WAITV(12) MF1(2) ISSUE1(6)
      WAITV(12) MF1(3) ISSUE1(7)
      WAITV(12) MF1(4)
      WAITV(8)  MF1(5)
      WAITV(4)  MF1(6)
      WAITV(0)  MF1(7)
#undef ISSUE1
#undef MF1

      CRED_AND_POINTWISE(hout, hall);
    }
  }
#undef POLLG
#undef CRED_AND_POINTWISE
#undef GLD_X
#undef GLD_C
#undef WAITV
}

// ---------------- final FC ----------------
__global__ __launch_bounds__(512, 1)
void k_fc(const f16* __restrict__ h1all, const f16* __restrict__ Wfc16,
          const float* __restrict__ bfc, float* __restrict__ out) {
  const int s = blockIdx.x;
  const f16* A = h1all + (size_t)s * 65536;
  __shared__ float credf[8][64][68];

  const int w = threadIdx.x >> 6;
  const int lane = threadIdx.x & 63;
  const int l15 = lane & 15;
  const int ksub = (lane >> 4) << 3;

  f32x4 acc[4][4];
#pragma unroll
  for (int i = 0; i < 4; ++i)
#pragma unroll
    for (int j = 0; j < 4; ++j) acc[i][j] = f32x4{0.f, 0.f, 0.f, 0.f};

  const int kbeg = w * 128, kend = kbeg + 128;
  f16x8 af0[4], bf0[4], af1[4], bf1[4];

  auto LOADK = [&](int kc, f16x8(&a)[4], f16x8(&b)[4]) {
    const f16* ap = A + kc + ksub;
#pragma unroll
    for (int rf = 0; rf < 4; ++rf)
      a[rf] = *(const f16x8*)(ap + (size_t)(rf * 16 + l15) * 1024);
    const f16* bp = Wfc16 + kc + ksub;
#pragma unroll
    for (int cf = 0; cf < 4; ++cf)
      b[cf] = *(const f16x8*)(bp + (size_t)(cf * 16 + l15) * 1024);
  };

  LOADK(kbeg, af0, bf0);
  for (int kc = kbeg; kc < kend; kc += 64) {
    LOADK(kc + 32, af1, bf1);
#pragma unroll
    for (int rf = 0; rf < 4; ++rf)
#pragma unroll
      for (int cf = 0; cf < 4; ++cf) acc[rf][cf] = MFMA16(af0[rf], bf0[cf], acc[rf][cf]);
    if (kc + 64 < kend) LOADK(kc + 64, af0, bf0);
#pragma unroll
    for (int rf = 0; rf < 4; ++rf)
#pragma unroll
      for (int cf = 0; cf < 4; ++cf) acc[rf][cf] = MFMA16(af1[rf], bf1[cf], acc[rf][cf]);
  }

#pragma unroll
  for (int rf = 0; rf < 4; ++rf)
#pragma unroll
    for (int cf = 0; cf < 4; ++cf)
#pragma unroll
      for (int r = 0; r < 4; ++r)
        credf[w][rf * 16 + (lane >> 4) * 4 + r][cf * 16 + l15] = acc[rf][cf][r];

  __syncthreads();

  int m = threadIdx.x >> 3;
  int cbase = (threadIdx.x & 7) * 8;
#pragma unroll
  for (int u = 0; u < 8; ++u) {
    int col = cbase + u;
    float v = bfc[col];
#pragma unroll
    for (int ww = 0; ww < 8; ++ww) v += credf[ww][m][col];
    out[((size_t)m * 512 + s) * 64 + col] = v;
  }
}

// ---------------- host ----------------
extern "C" void kernel_launch(void* const* d_in, const int* in_sizes, int n_in,
                              void* d_out, int out_size, void* d_ws, size_t ws_size,
                              hipStream_t stream) {
  const float* x    = (const float*)d_in[0];
  const float* Wih0 = (const float*)d_in[1];
  const float* Whh0 = (const float*)d_in[2];
  const float* bih0 = (const float*)d_in[3];
  const float* bhh0 = (const float*)d_in[4];
  const float* Wih1 = (const float*)d_in[5];
  const float* Whh1 = (const float*)d_in[6];
  const float* bih1 = (const float*)d_in[7];
  const float* bhh1 = (const float*)d_in[8];
  const float* Wfc  = (const float*)d_in[9];
  const float* bfc  = (const float*)d_in[10];
  float* out = (float*)d_out;

  char* ws = (char*)d_ws;
  f16*   W0f   = (f16*)(ws + 0);           // 12288 frags * 1KB = 12,582,912
  f16*   W1f   = (f16*)(ws + 12582912);    // 16384 frags * 1KB = 16,777,216
  f16*   Wfc16 = (f16*)(ws + 29360128);    // 131,072
  float* b0r   = (float*)(ws + 29491200);  // 16,384
  float* b1r   = (float*)(ws + 29507584);  // 16,384
  f16*   x16   = (f16*)(ws + 29523968);    // 33,554,432
  f16*   h1all = (f16*)(ws + 63078400);    // 67,108,864
  f16*   h0buf = (f16*)(ws + 130187264);   // 4 * 131,072 = 524,288
  f16*   h1buf = (f16*)(ws + 130711552);   // 524,288
  int*   flags = (int*)(ws + 131235840);   // 32,768
  int*   gfl   = (int*)(ws + 131268608);   // 64 B (one cache line, 16 ints)

  k_conv_x<<<8192, 256, 0, stream>>>(x, x16);
  k_conv_wfrag<<<12288, 64, 0, stream>>>(Wih0, Whh0, W0f, 512, 6, 192);
  k_conv_wfrag<<<16384, 64, 0, stream>>>(Wih1, Whh1, W1f, 1024, 8, 256);
  k_conv_bias<<<64, 64, 0, stream>>>(bih0, bhh0, b0r);
  k_conv_bias<<<64, 64, 0, stream>>>(bih1, bhh1, b1r);
  k_conv_wfc<<<256, 256, 0, stream>>>(Wfc, Wfc16);
  // zero h ring buffers + flags + gflags every launch (graph-replay determinism)
  hipMemsetAsync(ws + 130187264, 0, 524288 * 2 + 32768 + 64, stream);

  {
    const f16* x16c = x16; const f16* W0fc = W0f; const float* b0rc = b0r;
    const f16* W1fc = W1f; const float* b1rc = b1r;
    f16 *p0 = h0buf, *p1 = h1buf, *ph = h1all;
    int* fl = flags; int* gf = gfl;
    void* kargs[] = { &x16c, &W0fc, &b0rc, &W1fc, &b1rc, &p0, &p1, &ph, &fl, &gf };
    hipLaunchCooperativeKernel((void*)k_persist, dim3(256), dim3(512), kargs, 0, stream);
  }

  k_fc<<<512, 512, 0, stream>>>(h1all, Wfc16, bfc, out);
}